// Round 16
// baseline (191.133 us; speedup 1.0000x reference)
//
#include <hip/hip_runtime.h>
#include <math.h>

#define N_NODES 50000
#define IN_CH   512
#define HID     8
#define HEADS   8
#define C1      64      // HEADS*HID
#define OUT_CH  40
#define NEG_SLOPE 0.2f
#define NB      ((N_NODES + 255) / 256)   // 196 coarse buckets (dst>>8)
#define PART_TILE 8192                    // edges per k_part block
#define CAP     16384                     // per-bucket capacity (mean 8163)

__device__ __forceinline__ float leaky(float v) { return fmaxf(v, NEG_SLOPE * v); }
// logits are tiny (|a| < ~0.1): native v_exp_f32 path is exact enough (<=2ulp)
__device__ __forceinline__ float fexp(float v) { return __expf(v); }

typedef __attribute__((ext_vector_type(8))) short short8;
typedef __attribute__((ext_vector_type(4))) short short4v;
typedef __attribute__((ext_vector_type(4))) float f32x4;

__device__ __forceinline__ unsigned short f2bf(float f) {
    unsigned u = __builtin_bit_cast(unsigned, f);
    u += 0x7FFFu + ((u >> 16) & 1u);          // round-to-nearest-even
    return (unsigned short)(u >> 16);
}
__device__ __forceinline__ float bf2f(unsigned short h) {
    unsigned u = ((unsigned)h) << 16;
    return __builtin_bit_cast(float, u);
}

#define XH_STRIDE_B 272   // bytes per LDS row: 128 bf16 = 256B + 16 pad

// ---------------------------------------------------------------------------
// Pack W1 (512x64 fp32) into MFMA B-fragment order, bf16 hi/lo.
// ---------------------------------------------------------------------------
__global__ __launch_bounds__(256) void k_packW(
    const float* __restrict__ W1, short* __restrict__ bph, short* __restrict__ bpl)
{
    const int idx = blockIdx.x * 256 + threadIdx.x;
    if (idx >= 512 * 64) return;
    const int k = idx >> 6, col = idx & 63;
    const float w = W1[idx];
    const unsigned short hi = f2bf(w);
    const unsigned short lo = f2bf(w - bf2f(hi));
    const int di = ((k >> 5) * 64 + col) * 32 + (k & 31);
    bph[di] = (short)hi;
    bpl[di] = (short)lo;
}

// ---------------------------------------------------------------------------
// K1 (MFMA): h1 = (x @ W1) / rowsum(x), bf16x3 split, software-pipelined.
// ---------------------------------------------------------------------------
__global__ __launch_bounds__(256) void k_gemm1_mfma(
    const float* __restrict__ x,
    const short* __restrict__ bph, const short* __restrict__ bpl,
    const float* __restrict__ attS, const float* __restrict__ attD,
    unsigned short* __restrict__ h1b, float* __restrict__ aS, float* __restrict__ aD)
{
    __shared__ unsigned char smem[17536];
    short* xh = (short*)smem;                      // [32] rows x 136 shorts
    short* xl = (short*)(smem + 8704);
    float* rowsum = (float*)(smem + 17408);        // [32]
    float* houtf  = (float*)smem;                  // [32][68] (aliases xh/xl)

    const int tid  = threadIdx.x;
    const int lane = tid & 63;
    const int w    = tid >> 6;
    const int row_off = (w & 1) * 16;
    const int col_off = (w >> 1) * 32;
    const int rowBase = blockIdx.x * 32;

    const int l15 = lane & 15;
    const int kg  = lane >> 4;
    const int a_base = (l15 + row_off) * XH_STRIDE_B + kg * 16;

    const int srow = tid >> 5;          // staging row-group 0..7
    const int sk4  = tid & 31;          // staging k4 slot

    f32x4 acc0 = {0.f, 0.f, 0.f, 0.f};
    f32x4 acc1 = {0.f, 0.f, 0.f, 0.f};
    float psum[4] = {0.f, 0.f, 0.f, 0.f};
    float4 va[4], vb[4];

    auto LOAD = [&](int c, float4 (&v)[4]) {
        #pragma unroll
        for (int i = 0; i < 4; ++i) {
            const int grow = rowBase + i * 8 + srow;
            v[i] = (grow < N_NODES)
                 ? *(const float4*)(x + (size_t)grow * IN_CH + c * 128 + sk4 * 4)
                 : make_float4(0.f, 0.f, 0.f, 0.f);
        }
    };
    auto STAGE = [&](float4 (&v)[4]) {
        #pragma unroll
        for (int i = 0; i < 4; ++i) {
            const int row = i * 8 + srow;
            const unsigned short h0 = f2bf(v[i].x), h1u = f2bf(v[i].y),
                                 h2 = f2bf(v[i].z), h3  = f2bf(v[i].w);
            short4v hvv = { (short)h0, (short)h1u, (short)h2, (short)h3 };
            short4v lvv = { (short)f2bf(v[i].x - bf2f(h0)), (short)f2bf(v[i].y - bf2f(h1u)),
                            (short)f2bf(v[i].z - bf2f(h2)), (short)f2bf(v[i].w - bf2f(h3)) };
            *(short4v*)((char*)xh + row * XH_STRIDE_B + sk4 * 8) = hvv;
            *(short4v*)((char*)xl + row * XH_STRIDE_B + sk4 * 8) = lvv;
            psum[i] += v[i].x + v[i].y + v[i].z + v[i].w;
        }
    };
    auto MFMA = [&](int c) {
        #pragma unroll
        for (int kk2 = 0; kk2 < 4; ++kk2) {
            const int kk = c * 4 + kk2;
            const short8 ah = *(const short8*)((const char*)xh + a_base + kk2 * 64);
            const short8 al = *(const short8*)((const char*)xl + a_base + kk2 * 64);
            const int b0 = (kk * 64 + col_off + l15) * 32 + kg * 8;
            const int b1 = b0 + 16 * 32;
            const short8 bh0 = *(const short8*)(bph + b0);
            const short8 bl0 = *(const short8*)(bpl + b0);
            const short8 bh1 = *(const short8*)(bph + b1);
            const short8 bl1 = *(const short8*)(bpl + b1);
            acc0 = __builtin_amdgcn_mfma_f32_16x16x32_bf16(ah, bh0, acc0, 0, 0, 0);
            acc1 = __builtin_amdgcn_mfma_f32_16x16x32_bf16(ah, bh1, acc1, 0, 0, 0);
            acc0 = __builtin_amdgcn_mfma_f32_16x16x32_bf16(ah, bl0, acc0, 0, 0, 0);
            acc1 = __builtin_amdgcn_mfma_f32_16x16x32_bf16(ah, bl1, acc1, 0, 0, 0);
            acc0 = __builtin_amdgcn_mfma_f32_16x16x32_bf16(al, bh0, acc0, 0, 0, 0);
            acc1 = __builtin_amdgcn_mfma_f32_16x16x32_bf16(al, bh1, acc1, 0, 0, 0);
        }
    };

    LOAD(0, va);
    STAGE(va);
    __syncthreads();
    LOAD(1, vb);
    MFMA(0);
    __syncthreads();
    STAGE(vb);
    __syncthreads();
    LOAD(2, va);
    MFMA(1);
    __syncthreads();
    STAGE(va);
    __syncthreads();
    LOAD(3, vb);
    MFMA(2);
    __syncthreads();
    STAGE(vb);
    #pragma unroll
    for (int i = 0; i < 4; ++i) {
        float s = psum[i];
        #pragma unroll
        for (int off = 16; off; off >>= 1) s += __shfl_xor(s, off, 32);
        if (sk4 == 0) rowsum[i * 8 + srow] = s;
    }
    __syncthreads();
    MFMA(3);
    __syncthreads();

    #pragma unroll
    for (int r = 0; r < 4; ++r) {
        const int row = row_off + kg * 4 + r;   // C/D: row=(lane>>4)*4+reg
        const float rs = fmaxf(rowsum[row], 1e-8f);
        houtf[row * 68 + col_off + l15]      = acc0[r] / rs;
        houtf[row * 68 + col_off + 16 + l15] = acc1[r] / rs;
    }
    __syncthreads();

    // coalesced h1 write (bf16)
    #pragma unroll
    for (int i = tid; i < 32 * 16; i += 256) {
        const int row = i >> 4, seg = i & 15;
        if (rowBase + row < N_NODES) {
            const float* hs = houtf + row * 68 + seg * 4;
            short4v o = { (short)f2bf(hs[0]), (short)f2bf(hs[1]),
                          (short)f2bf(hs[2]), (short)f2bf(hs[3]) };
            *(short4v*)(h1b + (size_t)(rowBase + row) * 64 + seg * 4) = o;
        }
    }

    // logits: thread = (row, head), from fp32 LDS copy
    {
        const int row = tid >> 3, hd = tid & 7;
        if (rowBase + row < N_NODES) {
            float vs = 0.f, vd = 0.f;
            #pragma unroll
            for (int e2 = 0; e2 < 8; ++e2) {
                const float hv = houtf[row * 68 + hd * 8 + e2];
                vs = fmaf(hv, attS[hd * 8 + e2], vs);
                vd = fmaf(hv, attD[hd * 8 + e2], vd);
            }
            aS[(size_t)(rowBase + row) * 8 + hd] = vs;
            aD[(size_t)(rowBase + row) * 8 + hd] = vd;
        }
    }
}

// ---------------------------------------------------------------------------
// init per-bucket cursors to fixed bases b*CAP (no count pass needed)
// ---------------------------------------------------------------------------
__global__ __launch_bounds__(256) void k_initCur(int* __restrict__ coarseCur)
{
    const int t = threadIdx.x;
    if (t < NB) coarseCur[t] = t * CAP;
}

// ---------------------------------------------------------------------------
// Pass A: coarse partition into fixed-capacity buckets; payload packed
// (src | dlocal<<17). PART_TILE=8192 halves scan/barrier overhead.
// ---------------------------------------------------------------------------
__global__ __launch_bounds__(256) void k_part(
    const int* __restrict__ src, const int* __restrict__ dst, int E,
    int* __restrict__ coarseCur, unsigned int* __restrict__ pairs)
{
    __shared__ int  hist[256];
    __shared__ int  scn[256];
    __shared__ int  offs[256];
    __shared__ unsigned int  pairBuf[PART_TILE];
    __shared__ unsigned char bktBuf[PART_TILE];

    const int t = threadIdx.x;
    const int tileBase = blockIdx.x * PART_TILE;
    const int n = min(PART_TILE, E - tileBase);

    hist[t] = 0;
    __syncthreads();

    for (int e = t; e < n; e += 256)
        atomicAdd(&hist[dst[tileBase + e] >> 8], 1);
    __syncthreads();

    scn[t] = hist[t];
    __syncthreads();
    #pragma unroll
    for (int off = 1; off < 256; off <<= 1) {
        int xv = (t >= off) ? scn[t - off] : 0;
        __syncthreads();
        scn[t] += xv;
        __syncthreads();
    }

    {
        const int h  = hist[t];
        const int ls = scn[t] - h;
        int off = 0;
        if (h > 0) {
            const int gbase = atomicAdd(&coarseCur[t], h);
            off = gbase - ls;
        }
        offs[t] = off;
        hist[t] = ls;
    }
    __syncthreads();

    for (int e = t; e < n; e += 256) {
        const int s = src[tileBase + e];
        const int d = dst[tileBase + e];
        const int bkt = d >> 8;
        const int pos = atomicAdd(&hist[bkt], 1);
        pairBuf[pos] = (unsigned)s | ((unsigned)(d & 255) << 17);
        bktBuf[pos]  = (unsigned char)bkt;
    }
    __syncthreads();

    for (int i = t; i < n; i += 256)
        pairs[i + offs[bktBuf[i]]] = pairBuf[i];
}

// ---------------------------------------------------------------------------
// Pass B: per coarse bucket: fine histogram -> scan -> cumS/cumE -> scatter.
// ---------------------------------------------------------------------------
__global__ __launch_bounds__(256) void k_fine2(
    const int* __restrict__ coarseCur,
    const unsigned int* __restrict__ pairs, int* __restrict__ ssrc,
    int* __restrict__ cumS, int* __restrict__ cumE)
{
    __shared__ int hist[256];
    __shared__ int scn[256];
    __shared__ int cur[256];
    const int b = blockIdx.x;
    const int t = threadIdx.x;
    const int dbase = b << 8;
    const int nd = min(256, N_NODES - dbase);
    const int lo = b * CAP;
    const int hi = coarseCur[b];          // lo + count

    hist[t] = 0;
    __syncthreads();
    for (int j = lo + t; j < hi; j += 256)
        atomicAdd(&hist[(pairs[j] >> 17) & 255], 1);
    __syncthreads();

    const int hv = hist[t];
    scn[t] = hv;
    __syncthreads();
    #pragma unroll
    for (int off = 1; off < 256; off <<= 1) {
        int xv = (t >= off) ? scn[t - off] : 0;
        __syncthreads();
        scn[t] += xv;
        __syncthreads();
    }
    if (t < nd) {
        cumS[dbase + t] = lo + scn[t] - hv;
        cumE[dbase + t] = lo + scn[t];
    }
    cur[t] = lo + scn[t] - hv;
    __syncthreads();

    for (int j = lo + t; j < hi; j += 256) {
        const unsigned int p = pairs[j];
        const int pos = atomicAdd(&cur[(p >> 17) & 255], 1);
        ssrc[pos] = (int)(p & 0x1FFFFu);
    }
}

// ---------------------------------------------------------------------------
// K-AGG1F: wave per node; lane = (edge e = lane>>3, chunk c = lane&7).
// Superrounds of 32 + rounds of 8 + masked tail. NO post-loop block barrier:
// hstage is wave-private (in-wave LDS ordering via waitcnt + wave_barrier),
// so straggler waves don't stall the block.
// FUSED epilogue: ELU -> LDS -> gemm2 vs transposed W2 (b128 reads).
// ---------------------------------------------------------------------------
__global__ __launch_bounds__(256) void k_agg1f(
    const int* __restrict__ cumS, const int* __restrict__ cumE,
    const int* __restrict__ ssrc,
    const float* __restrict__ aS, const float* __restrict__ aD,
    const unsigned short* __restrict__ h1b, const float* __restrict__ b1,
    const float* __restrict__ W2,
    const float* __restrict__ attS2, const float* __restrict__ attD2,
    unsigned short* __restrict__ h2b, float* __restrict__ a2s, float* __restrict__ a2d)
{
    __shared__ float w2sT[40 * 68];     // transposed W2 [j][k], row pad 68 (272B)
    __shared__ float hstage[4][64];     // ELU'd layer-1 rows, one per wave

    const int tid  = threadIdx.x;
    const int lane = tid & 63;
    const int w    = tid >> 6;
    const int node = __builtin_amdgcn_readfirstlane(blockIdx.x * 4 + w);
    const int e = lane >> 3;      // edge slot 0..7
    const int c = lane & 7;       // chunk == head

    // stage W2 transposed: w2sT[j][k] = W2[k*40+j]; linear read i = k*40+j
    for (int i = tid; i < 2560; i += 256) {
        const int k = i / 40, j = i - k * 40;
        w2sT[j * 68 + k] = W2[i];
    }
    __syncthreads();   // all waves must see w2sT before their epilogue

    const int start = cumS[node];
    const int end   = cumE[node];

    const float aDn = aD[(size_t)node * 8 + c];
    float acc[8] = {0.f, 0.f, 0.f, 0.f, 0.f, 0.f, 0.f, 0.f};
    float den = 0.f;

    if (e == 0) {   // self loop handled by the e==0 lane group
        const float e0 = fexp(leaky(aS[(size_t)node * 8 + c] + aDn));
        const short8 hv = *(const short8*)(h1b + (size_t)node * 64 + c * 8);
        #pragma unroll
        for (int j = 0; j < 8; ++j)
            acc[j] = e0 * bf2f((unsigned short)hv[j]);
        den = e0;
    }

    int base = start;
    // superrounds: 32 edges, 12 gathers in flight
    for (; base + 32 <= end; base += 32) {
        const int s0 = ssrc[base + e];
        const int s1 = ssrc[base + 8 + e];
        const int s2 = ssrc[base + 16 + e];
        const int s3 = ssrc[base + 24 + e];
        const float aa0 = aS[(size_t)s0 * 8 + c];
        const float aa1 = aS[(size_t)s1 * 8 + c];
        const float aa2 = aS[(size_t)s2 * 8 + c];
        const float aa3 = aS[(size_t)s3 * 8 + c];
        const short8 h0 = *(const short8*)(h1b + ((size_t)s0 << 6) + c * 8);
        const short8 h1v = *(const short8*)(h1b + ((size_t)s1 << 6) + c * 8);
        const short8 h2v = *(const short8*)(h1b + ((size_t)s2 << 6) + c * 8);
        const short8 h3v = *(const short8*)(h1b + ((size_t)s3 << 6) + c * 8);
        const float w0 = fexp(leaky(aa0 + aDn));
        const float w1 = fexp(leaky(aa1 + aDn));
        const float w2 = fexp(leaky(aa2 + aDn));
        const float w3 = fexp(leaky(aa3 + aDn));
        #pragma unroll
        for (int j = 0; j < 8; ++j) {
            acc[j] = fmaf(w0, bf2f((unsigned short)h0[j]), acc[j]);
            acc[j] = fmaf(w1, bf2f((unsigned short)h1v[j]), acc[j]);
            acc[j] = fmaf(w2, bf2f((unsigned short)h2v[j]), acc[j]);
            acc[j] = fmaf(w3, bf2f((unsigned short)h3v[j]), acc[j]);
        }
        den += w0 + w1 + w2 + w3;
    }
    // single rounds of 8
    for (; base + 8 <= end; base += 8) {
        const int s = ssrc[base + e];
        const float aa = aS[(size_t)s * 8 + c];
        const short8 hv = *(const short8*)(h1b + ((size_t)s << 6) + c * 8);
        const float wv = fexp(leaky(aa + aDn));
        #pragma unroll
        for (int j = 0; j < 8; ++j)
            acc[j] = fmaf(wv, bf2f((unsigned short)hv[j]), acc[j]);
        den += wv;
    }
    if (base < end) {          // masked tail (1..7 edges)
        const int nb  = end - base;
        const int idx = base + (e < nb ? e : nb - 1);
        const int s   = ssrc[idx];
        float wv = fexp(leaky(aS[(size_t)s * 8 + c] + aDn));
        if (e >= nb) wv = 0.f;
        const short8 hv = *(const short8*)(h1b + ((size_t)s << 6) + c * 8);
        #pragma unroll
        for (int j = 0; j < 8; ++j)
            acc[j] = fmaf(wv, bf2f((unsigned short)hv[j]), acc[j]);
        den += wv;
    }

    // reduce over e-dimension (lanes with equal c)
    #pragma unroll
    for (int m = 8; m < 64; m <<= 1) {
        den += __shfl_xor(den, m, 64);
        #pragma unroll
        for (int j = 0; j < 8; ++j)
            acc[j] += __shfl_xor(acc[j], m, 64);
    }

    if (e == 0) {   // lanes 0..7: finalize channels c*8..c*8+7 -> LDS
        const float dinv = 1.f / (den + 1e-16f);
        #pragma unroll
        for (int j = 0; j < 8; ++j) {
            const float v = acc[j] * dinv + b1[c * 8 + j];
            hstage[w][c * 8 + j] = v > 0.f ? v : (__expf(v) - 1.f);
        }
    }
    // wave-private LDS: order writes before reads within this wave only
    asm volatile("s_waitcnt lgkmcnt(0)" ::: "memory");
    __builtin_amdgcn_wave_barrier();
    __builtin_amdgcn_sched_barrier(0);

    // ---- fused gemm2: lane j computes h2[node][j] = helu_row . W2T[j][:]
    const int j = lane;
    float acc2 = 0.f;
    if (j < OUT_CH) {
        #pragma unroll
        for (int k4 = 0; k4 < 16; ++k4) {
            const f32x4 hv4 = *(const f32x4*)(&hstage[w][k4 * 4]);
            const f32x4 wv4 = *(const f32x4*)(&w2sT[j * 68 + k4 * 4]);
            acc2 = fmaf(hv4.x, wv4.x, acc2);
            acc2 = fmaf(hv4.y, wv4.y, acc2);
            acc2 = fmaf(hv4.z, wv4.z, acc2);
            acc2 = fmaf(hv4.w, wv4.w, acc2);
        }
    }
    float vs = (j < OUT_CH) ? acc2 * attS2[j] : 0.f;
    float vd = (j < OUT_CH) ? acc2 * attD2[j] : 0.f;
    #pragma unroll
    for (int off = 32; off; off >>= 1) {
        vs += __shfl_xor(vs, off, 64);
        vd += __shfl_xor(vd, off, 64);
    }
    if (j < OUT_CH) h2b[(size_t)node * 40 + j] = f2bf(acc2);
    if (j == 0) {
        a2s[node] = vs;
        a2d[node] = vd;
    }
}

// ---------------------------------------------------------------------------
// K-AGG2: wave per node; lane = (e = lane>>3, c = lane&7), chunks 0..4 carry
// channels (h2b stride 40). c<5 guard on gathers: dead chunks issue NO loads.
// den computed by all lanes (identical across c-groups).
// ---------------------------------------------------------------------------
__global__ __launch_bounds__(256) void k_agg2(
    const int* __restrict__ cumS, const int* __restrict__ cumE,
    const int* __restrict__ ssrc,
    const float* __restrict__ a2s, const float* __restrict__ a2d,
    const unsigned short* __restrict__ h2b, const float* __restrict__ b2,
    float* __restrict__ out)
{
    const int lane = threadIdx.x & 63;
    const int node = __builtin_amdgcn_readfirstlane(blockIdx.x * 4 + (threadIdx.x >> 6));
    const int e = lane >> 3;
    const int c = lane & 7;

    const int start = cumS[node];
    const int end   = cumE[node];

    const float aDd = a2d[node];
    float acc[8] = {0.f, 0.f, 0.f, 0.f, 0.f, 0.f, 0.f, 0.f};
    float den = 0.f;

    if (e == 0) {
        const float e0 = fexp(leaky(a2s[node] + aDd));
        if (c < 5) {
            const short8 hv = *(const short8*)(h2b + (size_t)node * 40 + c * 8);
            #pragma unroll
            for (int j = 0; j < 8; ++j)
                acc[j] = e0 * bf2f((unsigned short)hv[j]);
        }
        den = e0;
    }

    int base = start;
    for (; base + 32 <= end; base += 32) {
        const int s0 = ssrc[base + e];
        const int s1 = ssrc[base + 8 + e];
        const int s2 = ssrc[base + 16 + e];
        const int s3 = ssrc[base + 24 + e];
        const float aa0 = a2s[s0];
        const float aa1 = a2s[s1];
        const float aa2 = a2s[s2];
        const float aa3 = a2s[s3];
        short8 h0 = {0,0,0,0,0,0,0,0}, h1v = {0,0,0,0,0,0,0,0};
        short8 h2v = {0,0,0,0,0,0,0,0}, h3v = {0,0,0,0,0,0,0,0};
        if (c < 5) {
            h0  = *(const short8*)(h2b + (size_t)s0 * 40 + c * 8);
            h1v = *(const short8*)(h2b + (size_t)s1 * 40 + c * 8);
            h2v = *(const short8*)(h2b + (size_t)s2 * 40 + c * 8);
            h3v = *(const short8*)(h2b + (size_t)s3 * 40 + c * 8);
        }
        const float w0 = fexp(leaky(aa0 + aDd));
        const float w1 = fexp(leaky(aa1 + aDd));
        const float w2 = fexp(leaky(aa2 + aDd));
        const float w3 = fexp(leaky(aa3 + aDd));
        if (c < 5) {
            #pragma unroll
            for (int j = 0; j < 8; ++j) {
                acc[j] = fmaf(w0, bf2f((unsigned short)h0[j]), acc[j]);
                acc[j] = fmaf(w1, bf2f((unsigned short)h1v[j]), acc[j]);
                acc[j] = fmaf(w2, bf2f((unsigned short)h2v[j]), acc[j]);
                acc[j] = fmaf(w3, bf2f((unsigned short)h3v[j]), acc[j]);
            }
        }
        den += w0 + w1 + w2 + w3;
    }
    for (; base + 8 <= end; base += 8) {
        const int s = ssrc[base + e];
        const float aa = a2s[s];
        const float wv = fexp(leaky(aa + aDd));
        if (c < 5) {
            const short8 hv = *(const short8*)(h2b + (size_t)s * 40 + c * 8);
            #pragma unroll
            for (int j = 0; j < 8; ++j)
                acc[j] = fmaf(wv, bf2f((unsigned short)hv[j]), acc[j]);
        }
        den += wv;
    }
    if (base < end) {
        const int nb  = end - base;
        const int idx = base + (e < nb ? e : nb - 1);
        const int s   = ssrc[idx];
        float wv = fexp(leaky(a2s[s] + aDd));
        if (e >= nb) wv = 0.f;
        if (c < 5) {
            const short8 hv = *(const short8*)(h2b + (size_t)s * 40 + c * 8);
            #pragma unroll
            for (int j = 0; j < 8; ++j)
                acc[j] = fmaf(wv, bf2f((unsigned short)hv[j]), acc[j]);
        }
        den += wv;
    }

    #pragma unroll
    for (int m = 8; m < 64; m <<= 1) {
        den += __shfl_xor(den, m, 64);
        #pragma unroll
        for (int j = 0; j < 8; ++j)
            acc[j] += __shfl_xor(acc[j], m, 64);
    }

    if (e == 0 && c < 5) {   // lanes 0..4 write channels c*8..c*8+7
        const float dinv = 1.f / (den + 1e-16f);
        float o[8];
        #pragma unroll
        for (int j = 0; j < 8; ++j)
            o[j] = acc[j] * dinv + b2[c * 8 + j];
        float4* dst0 = (float4*)(out + (size_t)node * OUT_CH + c * 8);
        dst0[0] = make_float4(o[0], o[1], o[2], o[3]);
        dst0[1] = make_float4(o[4], o[5], o[6], o[7]);
    }
}

// ---------------------------------------------------------------------------
extern "C" void kernel_launch(void* const* d_in, const int* in_sizes, int n_in,
                              void* d_out, int out_size, void* d_ws, size_t ws_size,
                              hipStream_t stream)
{
    const float* x     = (const float*)d_in[0];
    const int*   ei    = (const int*)d_in[1];
    const float* W1    = (const float*)d_in[2];
    const float* attS1 = (const float*)d_in[3];
    const float* attD1 = (const float*)d_in[4];
    const float* b1    = (const float*)d_in[5];
    const float* W2    = (const float*)d_in[6];
    const float* attS2 = (const float*)d_in[7];
    const float* attD2 = (const float*)d_in[8];
    const float* b2    = (const float*)d_in[9];

    const int E = in_sizes[1] / 2;
    const int* src = ei;
    const int* dst = ei + E;

    float* out = (float*)d_out;
    float* f = (float*)d_ws;
    float* aS1  = f;  f += (size_t)N_NODES * 8;
    float* aD1  = f;  f += (size_t)N_NODES * 8;
    float* a2s  = f;  f += (size_t)N_NODES;
    float* a2d  = f;  f += (size_t)N_NODES;
    unsigned short* h1b = (unsigned short*)f;  f += (size_t)N_NODES * 32;  // bf16 [N][64]
    unsigned short* h2b = (unsigned short*)f;  f += (size_t)N_NODES * 20 + 64;  // bf16 [N][40] (+pad)
    short* bph = (short*)f;  f += 16384;        // 512*64 shorts (64 KB)
    short* bpl = (short*)f;  f += 16384;
    unsigned int* pairs = (unsigned int*)f;  f += (size_t)NB * CAP;
    int* ip = (int*)f;
    int* coarseCur = ip;  ip += 256;
    int* cumS      = ip;  ip += N_NODES;
    int* cumE      = ip;  ip += N_NODES;
    int* ssrc      = ip;  ip += (size_t)NB * CAP;

    const int partBlocks = (E + PART_TILE - 1) / PART_TILE;

    // ---- CSR build (fixed-capacity buckets; no count pass)
    k_initCur<<<1, 256, 0, stream>>>(coarseCur);
    k_part<<<partBlocks, 256, 0, stream>>>(src, dst, E, coarseCur, pairs);
    k_fine2<<<NB, 256, 0, stream>>>(coarseCur, pairs, ssrc, cumS, cumE);

    // ---- Layer 1 (agg fused with layer-2 GEMM + logits)
    k_packW<<<(512 * 64 + 255) / 256, 256, 0, stream>>>(W1, bph, bpl);
    k_gemm1_mfma<<<(N_NODES + 31) / 32, 256, 0, stream>>>(x, bph, bpl, attS1, attD1,
                                                          h1b, aS1, aD1);
    k_agg1f<<<N_NODES / 4, 256, 0, stream>>>(cumS, cumE, ssrc, aS1, aD1, h1b, b1,
                                             W2, attS2, attD2, h2b, a2s, a2d);

    // ---- Layer 2 aggregation
    k_agg2<<<N_NODES / 4, 256, 0, stream>>>(cumS, cumE, ssrc, a2s, a2d, h2b, b2, out);
}

// Round 17
// 188.494 us; speedup vs baseline: 1.0140x; 1.0140x over previous
//
#include <hip/hip_runtime.h>
#include <math.h>

#define N_NODES 50000
#define IN_CH   512
#define HID     8
#define HEADS   8
#define C1      64      // HEADS*HID
#define OUT_CH  40
#define NEG_SLOPE 0.2f
#define NB      ((N_NODES + 255) / 256)   // 196 coarse buckets (dst>>8)
#define PART_TILE 8192                    // edges per k_part block
#define CAP     16384                     // per-bucket capacity (mean 8163)

__device__ __forceinline__ float leaky(float v) { return fmaxf(v, NEG_SLOPE * v); }
// logits are tiny (|a| < ~0.1): native v_exp_f32 path is exact enough (<=2ulp)
__device__ __forceinline__ float fexp(float v) { return __expf(v); }

typedef __attribute__((ext_vector_type(8))) short short8;
typedef __attribute__((ext_vector_type(4))) short short4v;
typedef __attribute__((ext_vector_type(4))) float f32x4;

__device__ __forceinline__ unsigned short f2bf(float f) {
    unsigned u = __builtin_bit_cast(unsigned, f);
    u += 0x7FFFu + ((u >> 16) & 1u);          // round-to-nearest-even
    return (unsigned short)(u >> 16);
}
__device__ __forceinline__ float bf2f(unsigned short h) {
    unsigned u = ((unsigned)h) << 16;
    return __builtin_bit_cast(float, u);
}

#define XH_STRIDE_B 272   // bytes per LDS row: 128 bf16 = 256B + 16 pad

// ---------------------------------------------------------------------------
// Pack W1 (512x64 fp32) into MFMA B-fragment order, bf16 hi/lo.
// ---------------------------------------------------------------------------
__global__ __launch_bounds__(256) void k_packW(
    const float* __restrict__ W1, short* __restrict__ bph, short* __restrict__ bpl)
{
    const int idx = blockIdx.x * 256 + threadIdx.x;
    if (idx >= 512 * 64) return;
    const int k = idx >> 6, col = idx & 63;
    const float w = W1[idx];
    const unsigned short hi = f2bf(w);
    const unsigned short lo = f2bf(w - bf2f(hi));
    const int di = ((k >> 5) * 64 + col) * 32 + (k & 31);
    bph[di] = (short)hi;
    bpl[di] = (short)lo;
}

// ---------------------------------------------------------------------------
// K1 (MFMA): h1 = (x @ W1) / rowsum(x), bf16x3 split, software-pipelined.
// ---------------------------------------------------------------------------
__global__ __launch_bounds__(256) void k_gemm1_mfma(
    const float* __restrict__ x,
    const short* __restrict__ bph, const short* __restrict__ bpl,
    const float* __restrict__ attS, const float* __restrict__ attD,
    unsigned short* __restrict__ h1b, float* __restrict__ aS, float* __restrict__ aD)
{
    __shared__ unsigned char smem[17536];
    short* xh = (short*)smem;                      // [32] rows x 136 shorts
    short* xl = (short*)(smem + 8704);
    float* rowsum = (float*)(smem + 17408);        // [32]
    float* houtf  = (float*)smem;                  // [32][68] (aliases xh/xl)

    const int tid  = threadIdx.x;
    const int lane = tid & 63;
    const int w    = tid >> 6;
    const int row_off = (w & 1) * 16;
    const int col_off = (w >> 1) * 32;
    const int rowBase = blockIdx.x * 32;

    const int l15 = lane & 15;
    const int kg  = lane >> 4;
    const int a_base = (l15 + row_off) * XH_STRIDE_B + kg * 16;

    const int srow = tid >> 5;          // staging row-group 0..7
    const int sk4  = tid & 31;          // staging k4 slot

    f32x4 acc0 = {0.f, 0.f, 0.f, 0.f};
    f32x4 acc1 = {0.f, 0.f, 0.f, 0.f};
    float psum[4] = {0.f, 0.f, 0.f, 0.f};
    float4 va[4], vb[4];

    auto LOAD = [&](int c, float4 (&v)[4]) {
        #pragma unroll
        for (int i = 0; i < 4; ++i) {
            const int grow = rowBase + i * 8 + srow;
            v[i] = (grow < N_NODES)
                 ? *(const float4*)(x + (size_t)grow * IN_CH + c * 128 + sk4 * 4)
                 : make_float4(0.f, 0.f, 0.f, 0.f);
        }
    };
    auto STAGE = [&](float4 (&v)[4]) {
        #pragma unroll
        for (int i = 0; i < 4; ++i) {
            const int row = i * 8 + srow;
            const unsigned short h0 = f2bf(v[i].x), h1u = f2bf(v[i].y),
                                 h2 = f2bf(v[i].z), h3  = f2bf(v[i].w);
            short4v hvv = { (short)h0, (short)h1u, (short)h2, (short)h3 };
            short4v lvv = { (short)f2bf(v[i].x - bf2f(h0)), (short)f2bf(v[i].y - bf2f(h1u)),
                            (short)f2bf(v[i].z - bf2f(h2)), (short)f2bf(v[i].w - bf2f(h3)) };
            *(short4v*)((char*)xh + row * XH_STRIDE_B + sk4 * 8) = hvv;
            *(short4v*)((char*)xl + row * XH_STRIDE_B + sk4 * 8) = lvv;
            psum[i] += v[i].x + v[i].y + v[i].z + v[i].w;
        }
    };
    auto MFMA = [&](int c) {
        #pragma unroll
        for (int kk2 = 0; kk2 < 4; ++kk2) {
            const int kk = c * 4 + kk2;
            const short8 ah = *(const short8*)((const char*)xh + a_base + kk2 * 64);
            const short8 al = *(const short8*)((const char*)xl + a_base + kk2 * 64);
            const int b0 = (kk * 64 + col_off + l15) * 32 + kg * 8;
            const int b1 = b0 + 16 * 32;
            const short8 bh0 = *(const short8*)(bph + b0);
            const short8 bl0 = *(const short8*)(bpl + b0);
            const short8 bh1 = *(const short8*)(bph + b1);
            const short8 bl1 = *(const short8*)(bpl + b1);
            acc0 = __builtin_amdgcn_mfma_f32_16x16x32_bf16(ah, bh0, acc0, 0, 0, 0);
            acc1 = __builtin_amdgcn_mfma_f32_16x16x32_bf16(ah, bh1, acc1, 0, 0, 0);
            acc0 = __builtin_amdgcn_mfma_f32_16x16x32_bf16(ah, bl0, acc0, 0, 0, 0);
            acc1 = __builtin_amdgcn_mfma_f32_16x16x32_bf16(ah, bl1, acc1, 0, 0, 0);
            acc0 = __builtin_amdgcn_mfma_f32_16x16x32_bf16(al, bh0, acc0, 0, 0, 0);
            acc1 = __builtin_amdgcn_mfma_f32_16x16x32_bf16(al, bh1, acc1, 0, 0, 0);
        }
    };

    LOAD(0, va);
    STAGE(va);
    __syncthreads();
    LOAD(1, vb);
    MFMA(0);
    __syncthreads();
    STAGE(vb);
    __syncthreads();
    LOAD(2, va);
    MFMA(1);
    __syncthreads();
    STAGE(va);
    __syncthreads();
    LOAD(3, vb);
    MFMA(2);
    __syncthreads();
    STAGE(vb);
    #pragma unroll
    for (int i = 0; i < 4; ++i) {
        float s = psum[i];
        #pragma unroll
        for (int off = 16; off; off >>= 1) s += __shfl_xor(s, off, 32);
        if (sk4 == 0) rowsum[i * 8 + srow] = s;
    }
    __syncthreads();
    MFMA(3);
    __syncthreads();

    #pragma unroll
    for (int r = 0; r < 4; ++r) {
        const int row = row_off + kg * 4 + r;   // C/D: row=(lane>>4)*4+reg
        const float rs = fmaxf(rowsum[row], 1e-8f);
        houtf[row * 68 + col_off + l15]      = acc0[r] / rs;
        houtf[row * 68 + col_off + 16 + l15] = acc1[r] / rs;
    }
    __syncthreads();

    // coalesced h1 write (bf16)
    #pragma unroll
    for (int i = tid; i < 32 * 16; i += 256) {
        const int row = i >> 4, seg = i & 15;
        if (rowBase + row < N_NODES) {
            const float* hs = houtf + row * 68 + seg * 4;
            short4v o = { (short)f2bf(hs[0]), (short)f2bf(hs[1]),
                          (short)f2bf(hs[2]), (short)f2bf(hs[3]) };
            *(short4v*)(h1b + (size_t)(rowBase + row) * 64 + seg * 4) = o;
        }
    }

    // logits: thread = (row, head), from fp32 LDS copy
    {
        const int row = tid >> 3, hd = tid & 7;
        if (rowBase + row < N_NODES) {
            float vs = 0.f, vd = 0.f;
            #pragma unroll
            for (int e2 = 0; e2 < 8; ++e2) {
                const float hv = houtf[row * 68 + hd * 8 + e2];
                vs = fmaf(hv, attS[hd * 8 + e2], vs);
                vd = fmaf(hv, attD[hd * 8 + e2], vd);
            }
            aS[(size_t)(rowBase + row) * 8 + hd] = vs;
            aD[(size_t)(rowBase + row) * 8 + hd] = vd;
        }
    }
}

// ---------------------------------------------------------------------------
// init per-bucket cursors to fixed bases b*CAP (no count pass needed)
// ---------------------------------------------------------------------------
__global__ __launch_bounds__(256) void k_initCur(int* __restrict__ coarseCur)
{
    const int t = threadIdx.x;
    if (t < NB) coarseCur[t] = t * CAP;
}

// ---------------------------------------------------------------------------
// Pass A: coarse partition into fixed-capacity buckets; payload packed
// (src | dlocal<<17). PART_TILE=8192 halves scan/barrier overhead.
// ---------------------------------------------------------------------------
__global__ __launch_bounds__(256) void k_part(
    const int* __restrict__ src, const int* __restrict__ dst, int E,
    int* __restrict__ coarseCur, unsigned int* __restrict__ pairs)
{
    __shared__ int  hist[256];
    __shared__ int  scn[256];
    __shared__ int  offs[256];
    __shared__ unsigned int  pairBuf[PART_TILE];
    __shared__ unsigned char bktBuf[PART_TILE];

    const int t = threadIdx.x;
    const int tileBase = blockIdx.x * PART_TILE;
    const int n = min(PART_TILE, E - tileBase);

    hist[t] = 0;
    __syncthreads();

    for (int e = t; e < n; e += 256)
        atomicAdd(&hist[dst[tileBase + e] >> 8], 1);
    __syncthreads();

    scn[t] = hist[t];
    __syncthreads();
    #pragma unroll
    for (int off = 1; off < 256; off <<= 1) {
        int xv = (t >= off) ? scn[t - off] : 0;
        __syncthreads();
        scn[t] += xv;
        __syncthreads();
    }

    {
        const int h  = hist[t];
        const int ls = scn[t] - h;
        int off = 0;
        if (h > 0) {
            const int gbase = atomicAdd(&coarseCur[t], h);
            off = gbase - ls;
        }
        offs[t] = off;
        hist[t] = ls;
    }
    __syncthreads();

    for (int e = t; e < n; e += 256) {
        const int s = src[tileBase + e];
        const int d = dst[tileBase + e];
        const int bkt = d >> 8;
        const int pos = atomicAdd(&hist[bkt], 1);
        pairBuf[pos] = (unsigned)s | ((unsigned)(d & 255) << 17);
        bktBuf[pos]  = (unsigned char)bkt;
    }
    __syncthreads();

    for (int i = t; i < n; i += 256)
        pairs[i + offs[bktBuf[i]]] = pairBuf[i];
}

// ---------------------------------------------------------------------------
// Pass B: per coarse bucket: fine histogram -> scan -> cumS/cumE -> scatter.
// ---------------------------------------------------------------------------
__global__ __launch_bounds__(256) void k_fine2(
    const int* __restrict__ coarseCur,
    const unsigned int* __restrict__ pairs, int* __restrict__ ssrc,
    int* __restrict__ cumS, int* __restrict__ cumE)
{
    __shared__ int hist[256];
    __shared__ int scn[256];
    __shared__ int cur[256];
    const int b = blockIdx.x;
    const int t = threadIdx.x;
    const int dbase = b << 8;
    const int nd = min(256, N_NODES - dbase);
    const int lo = b * CAP;
    const int hi = coarseCur[b];          // lo + count

    hist[t] = 0;
    __syncthreads();
    for (int j = lo + t; j < hi; j += 256)
        atomicAdd(&hist[(pairs[j] >> 17) & 255], 1);
    __syncthreads();

    const int hv = hist[t];
    scn[t] = hv;
    __syncthreads();
    #pragma unroll
    for (int off = 1; off < 256; off <<= 1) {
        int xv = (t >= off) ? scn[t - off] : 0;
        __syncthreads();
        scn[t] += xv;
        __syncthreads();
    }
    if (t < nd) {
        cumS[dbase + t] = lo + scn[t] - hv;
        cumE[dbase + t] = lo + scn[t];
    }
    cur[t] = lo + scn[t] - hv;
    __syncthreads();

    for (int j = lo + t; j < hi; j += 256) {
        const unsigned int p = pairs[j];
        const int pos = atomicAdd(&cur[(p >> 17) & 255], 1);
        ssrc[pos] = (int)(p & 0x1FFFFu);
    }
}

// ---------------------------------------------------------------------------
// K-AGG1F: wave per node; lane = (edge e = lane>>3, chunk c = lane&7).
// Superrounds of 32 + rounds of 8 + masked tail. No post-loop block barrier:
// hstage is wave-private (waitcnt + wave_barrier); w2s ordered by the start
// __syncthreads. w2s kept in ORIGINAL [k][j] layout: lane j reads
// w2s[k*40+j] -> consecutive words, conflict-free (r16's transpose caused
// 5-way conflicts via stride 68).
// ---------------------------------------------------------------------------
__global__ __launch_bounds__(256) void k_agg1f(
    const int* __restrict__ cumS, const int* __restrict__ cumE,
    const int* __restrict__ ssrc,
    const float* __restrict__ aS, const float* __restrict__ aD,
    const unsigned short* __restrict__ h1b, const float* __restrict__ b1,
    const float* __restrict__ W2,
    const float* __restrict__ attS2, const float* __restrict__ attD2,
    unsigned short* __restrict__ h2b, float* __restrict__ a2s, float* __restrict__ a2d)
{
    __shared__ float w2s[64 * 40];      // 10.0 KB, [k][j]
    __shared__ float hstage[4][64];     // ELU'd layer-1 rows, one per wave

    const int tid  = threadIdx.x;
    const int lane = tid & 63;
    const int w    = tid >> 6;
    const int node = __builtin_amdgcn_readfirstlane(blockIdx.x * 4 + w);
    const int e = lane >> 3;      // edge slot 0..7
    const int c = lane & 7;       // chunk == head

    // stage W2 (coalesced float4)
    #pragma unroll
    for (int i = tid; i < 640; i += 256)
        ((float4*)w2s)[i] = ((const float4*)W2)[i];
    __syncthreads();   // all waves see w2s before their epilogue

    const int start = cumS[node];
    const int end   = cumE[node];

    const float aDn = aD[(size_t)node * 8 + c];
    float acc[8] = {0.f, 0.f, 0.f, 0.f, 0.f, 0.f, 0.f, 0.f};
    float den = 0.f;

    if (e == 0) {   // self loop handled by the e==0 lane group
        const float e0 = fexp(leaky(aS[(size_t)node * 8 + c] + aDn));
        const short8 hv = *(const short8*)(h1b + (size_t)node * 64 + c * 8);
        #pragma unroll
        for (int j = 0; j < 8; ++j)
            acc[j] = e0 * bf2f((unsigned short)hv[j]);
        den = e0;
    }

    int base = start;
    // superrounds: 32 edges, 12 gathers in flight
    for (; base + 32 <= end; base += 32) {
        const int s0 = ssrc[base + e];
        const int s1 = ssrc[base + 8 + e];
        const int s2 = ssrc[base + 16 + e];
        const int s3 = ssrc[base + 24 + e];
        const float aa0 = aS[(size_t)s0 * 8 + c];
        const float aa1 = aS[(size_t)s1 * 8 + c];
        const float aa2 = aS[(size_t)s2 * 8 + c];
        const float aa3 = aS[(size_t)s3 * 8 + c];
        const short8 h0 = *(const short8*)(h1b + ((size_t)s0 << 6) + c * 8);
        const short8 h1v = *(const short8*)(h1b + ((size_t)s1 << 6) + c * 8);
        const short8 h2v = *(const short8*)(h1b + ((size_t)s2 << 6) + c * 8);
        const short8 h3v = *(const short8*)(h1b + ((size_t)s3 << 6) + c * 8);
        const float w0 = fexp(leaky(aa0 + aDn));
        const float w1 = fexp(leaky(aa1 + aDn));
        const float w2 = fexp(leaky(aa2 + aDn));
        const float w3 = fexp(leaky(aa3 + aDn));
        #pragma unroll
        for (int j = 0; j < 8; ++j) {
            acc[j] = fmaf(w0, bf2f((unsigned short)h0[j]), acc[j]);
            acc[j] = fmaf(w1, bf2f((unsigned short)h1v[j]), acc[j]);
            acc[j] = fmaf(w2, bf2f((unsigned short)h2v[j]), acc[j]);
            acc[j] = fmaf(w3, bf2f((unsigned short)h3v[j]), acc[j]);
        }
        den += w0 + w1 + w2 + w3;
    }
    // single rounds of 8
    for (; base + 8 <= end; base += 8) {
        const int s = ssrc[base + e];
        const float aa = aS[(size_t)s * 8 + c];
        const short8 hv = *(const short8*)(h1b + ((size_t)s << 6) + c * 8);
        const float wv = fexp(leaky(aa + aDn));
        #pragma unroll
        for (int j = 0; j < 8; ++j)
            acc[j] = fmaf(wv, bf2f((unsigned short)hv[j]), acc[j]);
        den += wv;
    }
    if (base < end) {          // masked tail (1..7 edges)
        const int nb  = end - base;
        const int idx = base + (e < nb ? e : nb - 1);
        const int s   = ssrc[idx];
        float wv = fexp(leaky(aS[(size_t)s * 8 + c] + aDn));
        if (e >= nb) wv = 0.f;
        const short8 hv = *(const short8*)(h1b + ((size_t)s << 6) + c * 8);
        #pragma unroll
        for (int j = 0; j < 8; ++j)
            acc[j] = fmaf(wv, bf2f((unsigned short)hv[j]), acc[j]);
        den += wv;
    }

    // reduce over e-dimension (lanes with equal c)
    #pragma unroll
    for (int m = 8; m < 64; m <<= 1) {
        den += __shfl_xor(den, m, 64);
        #pragma unroll
        for (int j = 0; j < 8; ++j)
            acc[j] += __shfl_xor(acc[j], m, 64);
    }

    if (e == 0) {   // lanes 0..7: finalize channels c*8..c*8+7 -> LDS
        const float dinv = 1.f / (den + 1e-16f);
        #pragma unroll
        for (int j = 0; j < 8; ++j) {
            const float v = acc[j] * dinv + b1[c * 8 + j];
            hstage[w][c * 8 + j] = v > 0.f ? v : (__expf(v) - 1.f);
        }
    }
    // wave-private LDS: order writes before reads within this wave only
    asm volatile("s_waitcnt lgkmcnt(0)" ::: "memory");
    __builtin_amdgcn_wave_barrier();
    __builtin_amdgcn_sched_barrier(0);

    // ---- fused gemm2: lane j computes h2[node][j] = helu_row . W2[:,j]
    const int j = lane;
    float acc2 = 0.f;
    if (j < OUT_CH) {
        #pragma unroll
        for (int k = 0; k < 64; ++k)
            acc2 = fmaf(hstage[w][k], w2s[k * 40 + j], acc2);
    }
    float vs = (j < OUT_CH) ? acc2 * attS2[j] : 0.f;
    float vd = (j < OUT_CH) ? acc2 * attD2[j] : 0.f;
    #pragma unroll
    for (int off = 32; off; off >>= 1) {
        vs += __shfl_xor(vs, off, 64);
        vd += __shfl_xor(vd, off, 64);
    }
    if (j < OUT_CH) h2b[(size_t)node * 40 + j] = f2bf(acc2);
    if (j == 0) {
        a2s[node] = vs;
        a2d[node] = vd;
    }
}

// ---------------------------------------------------------------------------
// K-AGG2: wave per node; lane = (e = lane>>3, c = lane&7), chunks 0..4 carry
// channels (h2b stride 40). c<5 guard on gathers: dead chunks issue NO loads.
// ---------------------------------------------------------------------------
__global__ __launch_bounds__(256) void k_agg2(
    const int* __restrict__ cumS, const int* __restrict__ cumE,
    const int* __restrict__ ssrc,
    const float* __restrict__ a2s, const float* __restrict__ a2d,
    const unsigned short* __restrict__ h2b, const float* __restrict__ b2,
    float* __restrict__ out)
{
    const int lane = threadIdx.x & 63;
    const int node = __builtin_amdgcn_readfirstlane(blockIdx.x * 4 + (threadIdx.x >> 6));
    const int e = lane >> 3;
    const int c = lane & 7;

    const int start = cumS[node];
    const int end   = cumE[node];

    const float aDd = a2d[node];
    float acc[8] = {0.f, 0.f, 0.f, 0.f, 0.f, 0.f, 0.f, 0.f};
    float den = 0.f;

    if (e == 0) {
        const float e0 = fexp(leaky(a2s[node] + aDd));
        if (c < 5) {
            const short8 hv = *(const short8*)(h2b + (size_t)node * 40 + c * 8);
            #pragma unroll
            for (int j = 0; j < 8; ++j)
                acc[j] = e0 * bf2f((unsigned short)hv[j]);
        }
        den = e0;
    }

    int base = start;
    for (; base + 32 <= end; base += 32) {
        const int s0 = ssrc[base + e];
        const int s1 = ssrc[base + 8 + e];
        const int s2 = ssrc[base + 16 + e];
        const int s3 = ssrc[base + 24 + e];
        const float aa0 = a2s[s0];
        const float aa1 = a2s[s1];
        const float aa2 = a2s[s2];
        const float aa3 = a2s[s3];
        short8 h0 = {0,0,0,0,0,0,0,0}, h1v = {0,0,0,0,0,0,0,0};
        short8 h2v = {0,0,0,0,0,0,0,0}, h3v = {0,0,0,0,0,0,0,0};
        if (c < 5) {
            h0  = *(const short8*)(h2b + (size_t)s0 * 40 + c * 8);
            h1v = *(const short8*)(h2b + (size_t)s1 * 40 + c * 8);
            h2v = *(const short8*)(h2b + (size_t)s2 * 40 + c * 8);
            h3v = *(const short8*)(h2b + (size_t)s3 * 40 + c * 8);
        }
        const float w0 = fexp(leaky(aa0 + aDd));
        const float w1 = fexp(leaky(aa1 + aDd));
        const float w2 = fexp(leaky(aa2 + aDd));
        const float w3 = fexp(leaky(aa3 + aDd));
        if (c < 5) {
            #pragma unroll
            for (int j = 0; j < 8; ++j) {
                acc[j] = fmaf(w0, bf2f((unsigned short)h0[j]), acc[j]);
                acc[j] = fmaf(w1, bf2f((unsigned short)h1v[j]), acc[j]);
                acc[j] = fmaf(w2, bf2f((unsigned short)h2v[j]), acc[j]);
                acc[j] = fmaf(w3, bf2f((unsigned short)h3v[j]), acc[j]);
            }
        }
        den += w0 + w1 + w2 + w3;
    }
    for (; base + 8 <= end; base += 8) {
        const int s = ssrc[base + e];
        const float aa = a2s[s];
        const float wv = fexp(leaky(aa + aDd));
        if (c < 5) {
            const short8 hv = *(const short8*)(h2b + (size_t)s * 40 + c * 8);
            #pragma unroll
            for (int j = 0; j < 8; ++j)
                acc[j] = fmaf(wv, bf2f((unsigned short)hv[j]), acc[j]);
        }
        den += wv;
    }
    if (base < end) {
        const int nb  = end - base;
        const int idx = base + (e < nb ? e : nb - 1);
        const int s   = ssrc[idx];
        float wv = fexp(leaky(a2s[s] + aDd));
        if (e >= nb) wv = 0.f;
        if (c < 5) {
            const short8 hv = *(const short8*)(h2b + (size_t)s * 40 + c * 8);
            #pragma unroll
            for (int j = 0; j < 8; ++j)
                acc[j] = fmaf(wv, bf2f((unsigned short)hv[j]), acc[j]);
        }
        den += wv;
    }

    #pragma unroll
    for (int m = 8; m < 64; m <<= 1) {
        den += __shfl_xor(den, m, 64);
        #pragma unroll
        for (int j = 0; j < 8; ++j)
            acc[j] += __shfl_xor(acc[j], m, 64);
    }

    if (e == 0 && c < 5) {   // lanes 0..4 write channels c*8..c*8+7
        const float dinv = 1.f / (den + 1e-16f);
        float o[8];
        #pragma unroll
        for (int j = 0; j < 8; ++j)
            o[j] = acc[j] * dinv + b2[c * 8 + j];
        float4* dst0 = (float4*)(out + (size_t)node * OUT_CH + c * 8);
        dst0[0] = make_float4(o[0], o[1], o[2], o[3]);
        dst0[1] = make_float4(o[4], o[5], o[6], o[7]);
    }
}

// ---------------------------------------------------------------------------
extern "C" void kernel_launch(void* const* d_in, const int* in_sizes, int n_in,
                              void* d_out, int out_size, void* d_ws, size_t ws_size,
                              hipStream_t stream)
{
    const float* x     = (const float*)d_in[0];
    const int*   ei    = (const int*)d_in[1];
    const float* W1    = (const float*)d_in[2];
    const float* attS1 = (const float*)d_in[3];
    const float* attD1 = (const float*)d_in[4];
    const float* b1    = (const float*)d_in[5];
    const float* W2    = (const float*)d_in[6];
    const float* attS2 = (const float*)d_in[7];
    const float* attD2 = (const float*)d_in[8];
    const float* b2    = (const float*)d_in[9];

    const int E = in_sizes[1] / 2;
    const int* src = ei;
    const int* dst = ei + E;

    float* out = (float*)d_out;
    float* f = (float*)d_ws;
    float* aS1  = f;  f += (size_t)N_NODES * 8;
    float* aD1  = f;  f += (size_t)N_NODES * 8;
    float* a2s  = f;  f += (size_t)N_NODES;
    float* a2d  = f;  f += (size_t)N_NODES;
    unsigned short* h1b = (unsigned short*)f;  f += (size_t)N_NODES * 32;  // bf16 [N][64]
    unsigned short* h2b = (unsigned short*)f;  f += (size_t)N_NODES * 20 + 64;  // bf16 [N][40] (+pad)
    short* bph = (short*)f;  f += 16384;        // 512*64 shorts (64 KB)
    short* bpl = (short*)f;  f += 16384;
    unsigned int* pairs = (unsigned int*)f;  f += (size_t)NB * CAP;
    int* ip = (int*)f;
    int* coarseCur = ip;  ip += 256;
    int* cumS      = ip;  ip += N_NODES;
    int* cumE      = ip;  ip += N_NODES;
    int* ssrc      = ip;  ip += (size_t)NB * CAP;

    const int partBlocks = (E + PART_TILE - 1) / PART_TILE;

    // ---- CSR build (fixed-capacity buckets; no count pass)
    k_initCur<<<1, 256, 0, stream>>>(coarseCur);
    k_part<<<partBlocks, 256, 0, stream>>>(src, dst, E, coarseCur, pairs);
    k_fine2<<<NB, 256, 0, stream>>>(coarseCur, pairs, ssrc, cumS, cumE);

    // ---- Layer 1 (agg fused with layer-2 GEMM + logits)
    k_packW<<<(512 * 64 + 255) / 256, 256, 0, stream>>>(W1, bph, bpl);
    k_gemm1_mfma<<<(N_NODES + 31) / 32, 256, 0, stream>>>(x, bph, bpl, attS1, attD1,
                                                          h1b, aS1, aD1);
    k_agg1f<<<N_NODES / 4, 256, 0, stream>>>(cumS, cumE, ssrc, aS1, aD1, h1b, b1,
                                             W2, attS2, attD2, h2b, a2s, a2d);

    // ---- Layer 2 aggregation
    k_agg2<<<N_NODES / 4, 256, 0, stream>>>(cumS, cumE, ssrc, a2s, a2d, h2b, b2, out);
}

// Round 18
// 177.877 us; speedup vs baseline: 1.0745x; 1.0597x over previous
//
#include <hip/hip_runtime.h>
#include <math.h>

#define N_NODES 50000
#define IN_CH   512
#define HID     8
#define HEADS   8
#define C1      64      // HEADS*HID
#define OUT_CH  40
#define NEG_SLOPE 0.2f
#define NB      ((N_NODES + 255) / 256)   // 196 coarse buckets (dst>>8)
#define TILE    4096                      // edges per k_part block
#define CAP     16384                     // per-bucket capacity (mean 8163)

__device__ __forceinline__ float leaky(float v) { return fmaxf(v, NEG_SLOPE * v); }
// logits are tiny (|a| < ~0.1): native v_exp_f32 path is exact enough (<=2ulp)
__device__ __forceinline__ float fexp(float v) { return __expf(v); }

typedef __attribute__((ext_vector_type(8))) short short8;
typedef __attribute__((ext_vector_type(4))) short short4v;
typedef __attribute__((ext_vector_type(4))) float f32x4;

__device__ __forceinline__ unsigned short f2bf(float f) {
    unsigned u = __builtin_bit_cast(unsigned, f);
    u += 0x7FFFu + ((u >> 16) & 1u);          // round-to-nearest-even
    return (unsigned short)(u >> 16);
}
__device__ __forceinline__ float bf2f(unsigned short h) {
    unsigned u = ((unsigned)h) << 16;
    return __builtin_bit_cast(float, u);
}

#define XH_STRIDE_B 272   // bytes per LDS row: 128 bf16 = 256B + 16 pad

// ---------------------------------------------------------------------------
// Pack W1 (512x64 fp32) into MFMA B-fragment order, bf16 hi/lo.
// Block 0 additionally initializes the coarse-bucket cursors (b*CAP) --
// folded here to save a dispatch; k_part runs after (stream-ordered).
// ---------------------------------------------------------------------------
__global__ __launch_bounds__(256) void k_packW(
    const float* __restrict__ W1, short* __restrict__ bph, short* __restrict__ bpl,
    int* __restrict__ coarseCur)
{
    const int idx = blockIdx.x * 256 + threadIdx.x;
    if (blockIdx.x == 0 && threadIdx.x < NB)
        coarseCur[threadIdx.x] = threadIdx.x * CAP;
    if (idx >= 512 * 64) return;
    const int k = idx >> 6, col = idx & 63;
    const float w = W1[idx];
    const unsigned short hi = f2bf(w);
    const unsigned short lo = f2bf(w - bf2f(hi));
    const int di = ((k >> 5) * 64 + col) * 32 + (k & 31);
    bph[di] = (short)hi;
    bpl[di] = (short)lo;
}

// ---------------------------------------------------------------------------
// K1 (MFMA): h1 = (x @ W1) / rowsum(x), bf16x3 split, software-pipelined.
// ---------------------------------------------------------------------------
__global__ __launch_bounds__(256) void k_gemm1_mfma(
    const float* __restrict__ x,
    const short* __restrict__ bph, const short* __restrict__ bpl,
    const float* __restrict__ attS, const float* __restrict__ attD,
    unsigned short* __restrict__ h1b, float* __restrict__ aS, float* __restrict__ aD)
{
    __shared__ unsigned char smem[17536];
    short* xh = (short*)smem;                      // [32] rows x 136 shorts
    short* xl = (short*)(smem + 8704);
    float* rowsum = (float*)(smem + 17408);        // [32]
    float* houtf  = (float*)smem;                  // [32][68] (aliases xh/xl)

    const int tid  = threadIdx.x;
    const int lane = tid & 63;
    const int w    = tid >> 6;
    const int row_off = (w & 1) * 16;
    const int col_off = (w >> 1) * 32;
    const int rowBase = blockIdx.x * 32;

    const int l15 = lane & 15;
    const int kg  = lane >> 4;
    const int a_base = (l15 + row_off) * XH_STRIDE_B + kg * 16;

    const int srow = tid >> 5;          // staging row-group 0..7
    const int sk4  = tid & 31;          // staging k4 slot

    f32x4 acc0 = {0.f, 0.f, 0.f, 0.f};
    f32x4 acc1 = {0.f, 0.f, 0.f, 0.f};
    float psum[4] = {0.f, 0.f, 0.f, 0.f};
    float4 va[4], vb[4];

    auto LOAD = [&](int c, float4 (&v)[4]) {
        #pragma unroll
        for (int i = 0; i < 4; ++i) {
            const int grow = rowBase + i * 8 + srow;
            v[i] = (grow < N_NODES)
                 ? *(const float4*)(x + (size_t)grow * IN_CH + c * 128 + sk4 * 4)
                 : make_float4(0.f, 0.f, 0.f, 0.f);
        }
    };
    auto STAGE = [&](float4 (&v)[4]) {
        #pragma unroll
        for (int i = 0; i < 4; ++i) {
            const int row = i * 8 + srow;
            const unsigned short h0 = f2bf(v[i].x), h1u = f2bf(v[i].y),
                                 h2 = f2bf(v[i].z), h3  = f2bf(v[i].w);
            short4v hvv = { (short)h0, (short)h1u, (short)h2, (short)h3 };
            short4v lvv = { (short)f2bf(v[i].x - bf2f(h0)), (short)f2bf(v[i].y - bf2f(h1u)),
                            (short)f2bf(v[i].z - bf2f(h2)), (short)f2bf(v[i].w - bf2f(h3)) };
            *(short4v*)((char*)xh + row * XH_STRIDE_B + sk4 * 8) = hvv;
            *(short4v*)((char*)xl + row * XH_STRIDE_B + sk4 * 8) = lvv;
            psum[i] += v[i].x + v[i].y + v[i].z + v[i].w;
        }
    };
    auto MFMA = [&](int c) {
        #pragma unroll
        for (int kk2 = 0; kk2 < 4; ++kk2) {
            const int kk = c * 4 + kk2;
            const short8 ah = *(const short8*)((const char*)xh + a_base + kk2 * 64);
            const short8 al = *(const short8*)((const char*)xl + a_base + kk2 * 64);
            const int b0 = (kk * 64 + col_off + l15) * 32 + kg * 8;
            const int b1 = b0 + 16 * 32;
            const short8 bh0 = *(const short8*)(bph + b0);
            const short8 bl0 = *(const short8*)(bpl + b0);
            const short8 bh1 = *(const short8*)(bph + b1);
            const short8 bl1 = *(const short8*)(bpl + b1);
            acc0 = __builtin_amdgcn_mfma_f32_16x16x32_bf16(ah, bh0, acc0, 0, 0, 0);
            acc1 = __builtin_amdgcn_mfma_f32_16x16x32_bf16(ah, bh1, acc1, 0, 0, 0);
            acc0 = __builtin_amdgcn_mfma_f32_16x16x32_bf16(ah, bl0, acc0, 0, 0, 0);
            acc1 = __builtin_amdgcn_mfma_f32_16x16x32_bf16(ah, bl1, acc1, 0, 0, 0);
            acc0 = __builtin_amdgcn_mfma_f32_16x16x32_bf16(al, bh0, acc0, 0, 0, 0);
            acc1 = __builtin_amdgcn_mfma_f32_16x16x32_bf16(al, bh1, acc1, 0, 0, 0);
        }
    };

    LOAD(0, va);
    STAGE(va);
    __syncthreads();
    LOAD(1, vb);
    MFMA(0);
    __syncthreads();
    STAGE(vb);
    __syncthreads();
    LOAD(2, va);
    MFMA(1);
    __syncthreads();
    STAGE(va);
    __syncthreads();
    LOAD(3, vb);
    MFMA(2);
    __syncthreads();
    STAGE(vb);
    #pragma unroll
    for (int i = 0; i < 4; ++i) {
        float s = psum[i];
        #pragma unroll
        for (int off = 16; off; off >>= 1) s += __shfl_xor(s, off, 32);
        if (sk4 == 0) rowsum[i * 8 + srow] = s;
    }
    __syncthreads();
    MFMA(3);
    __syncthreads();

    #pragma unroll
    for (int r = 0; r < 4; ++r) {
        const int row = row_off + kg * 4 + r;   // C/D: row=(lane>>4)*4+reg
        const float rs = fmaxf(rowsum[row], 1e-8f);
        houtf[row * 68 + col_off + l15]      = acc0[r] / rs;
        houtf[row * 68 + col_off + 16 + l15] = acc1[r] / rs;
    }
    __syncthreads();

    // coalesced h1 write (bf16)
    #pragma unroll
    for (int i = tid; i < 32 * 16; i += 256) {
        const int row = i >> 4, seg = i & 15;
        if (rowBase + row < N_NODES) {
            const float* hs = houtf + row * 68 + seg * 4;
            short4v o = { (short)f2bf(hs[0]), (short)f2bf(hs[1]),
                          (short)f2bf(hs[2]), (short)f2bf(hs[3]) };
            *(short4v*)(h1b + (size_t)(rowBase + row) * 64 + seg * 4) = o;
        }
    }

    // logits: thread = (row, head), from fp32 LDS copy
    {
        const int row = tid >> 3, hd = tid & 7;
        if (rowBase + row < N_NODES) {
            float vs = 0.f, vd = 0.f;
            #pragma unroll
            for (int e2 = 0; e2 < 8; ++e2) {
                const float hv = houtf[row * 68 + hd * 8 + e2];
                vs = fmaf(hv, attS[hd * 8 + e2], vs);
                vd = fmaf(hv, attD[hd * 8 + e2], vd);
            }
            aS[(size_t)(rowBase + row) * 8 + hd] = vs;
            aD[(size_t)(rowBase + row) * 8 + hd] = vd;
        }
    }
}

// ---------------------------------------------------------------------------
// Pass A: coarse partition into fixed-capacity buckets; payload packed
// (src | dlocal<<17).
// ---------------------------------------------------------------------------
__global__ __launch_bounds__(256) void k_part(
    const int* __restrict__ src, const int* __restrict__ dst, int E,
    int* __restrict__ coarseCur, unsigned int* __restrict__ pairs)
{
    __shared__ int  hist[256];
    __shared__ int  scn[256];
    __shared__ int  offs[256];
    __shared__ unsigned int  pairBuf[TILE];
    __shared__ unsigned char bktBuf[TILE];

    const int t = threadIdx.x;
    const int tileBase = blockIdx.x * TILE;
    const int n = min(TILE, E - tileBase);

    hist[t] = 0;
    __syncthreads();

    for (int e = t; e < n; e += 256)
        atomicAdd(&hist[dst[tileBase + e] >> 8], 1);
    __syncthreads();

    scn[t] = hist[t];
    __syncthreads();
    #pragma unroll
    for (int off = 1; off < 256; off <<= 1) {
        int xv = (t >= off) ? scn[t - off] : 0;
        __syncthreads();
        scn[t] += xv;
        __syncthreads();
    }

    {
        const int h  = hist[t];
        const int ls = scn[t] - h;
        int off = 0;
        if (h > 0) {
            const int gbase = atomicAdd(&coarseCur[t], h);
            off = gbase - ls;
        }
        offs[t] = off;
        hist[t] = ls;
    }
    __syncthreads();

    for (int e = t; e < n; e += 256) {
        const int s = src[tileBase + e];
        const int d = dst[tileBase + e];
        const int bkt = d >> 8;
        const int pos = atomicAdd(&hist[bkt], 1);
        pairBuf[pos] = (unsigned)s | ((unsigned)(d & 255) << 17);
        bktBuf[pos]  = (unsigned char)bkt;
    }
    __syncthreads();

    for (int i = t; i < n; i += 256)
        pairs[i + offs[bktBuf[i]]] = pairBuf[i];
}

// ---------------------------------------------------------------------------
// Pass B: per coarse bucket: fine histogram -> scan -> cumS/cumE -> scatter.
// Buckets are gapped (base b*CAP); agg kernels use explicit start/end arrays.
// ---------------------------------------------------------------------------
__global__ __launch_bounds__(256) void k_fine2(
    const int* __restrict__ coarseCur,
    const unsigned int* __restrict__ pairs, int* __restrict__ ssrc,
    int* __restrict__ cumS, int* __restrict__ cumE)
{
    __shared__ int hist[256];
    __shared__ int scn[256];
    __shared__ int cur[256];
    const int b = blockIdx.x;
    const int t = threadIdx.x;
    const int dbase = b << 8;
    const int nd = min(256, N_NODES - dbase);
    const int lo = b * CAP;
    const int hi = coarseCur[b];          // lo + count

    hist[t] = 0;
    __syncthreads();
    for (int j = lo + t; j < hi; j += 256)
        atomicAdd(&hist[(pairs[j] >> 17) & 255], 1);
    __syncthreads();

    const int hv = hist[t];
    scn[t] = hv;
    __syncthreads();
    #pragma unroll
    for (int off = 1; off < 256; off <<= 1) {
        int xv = (t >= off) ? scn[t - off] : 0;
        __syncthreads();
        scn[t] += xv;
        __syncthreads();
    }
    if (t < nd) {
        cumS[dbase + t] = lo + scn[t] - hv;
        cumE[dbase + t] = lo + scn[t];
    }
    cur[t] = lo + scn[t] - hv;
    __syncthreads();

    for (int j = lo + t; j < hi; j += 256) {
        const unsigned int p = pairs[j];
        const int pos = atomicAdd(&cur[(p >> 17) & 255], 1);
        ssrc[pos] = (int)(p & 0x1FFFFu);
    }
}

// ---------------------------------------------------------------------------
// K-AGG1F: wave per node; lane = (edge e = lane>>3, chunk c = lane&7).
// Superrounds of 32 edges (12 gathers in flight) + rounds of 8 + masked tail.
// FUSED epilogue: ELU -> LDS -> gemm2 (64x40 matvec) -> h2b + logits.
// ---------------------------------------------------------------------------
__global__ __launch_bounds__(256) void k_agg1f(
    const int* __restrict__ cumS, const int* __restrict__ cumE,
    const int* __restrict__ ssrc,
    const float* __restrict__ aS, const float* __restrict__ aD,
    const unsigned short* __restrict__ h1b, const float* __restrict__ b1,
    const float* __restrict__ W2,
    const float* __restrict__ attS2, const float* __restrict__ attD2,
    unsigned short* __restrict__ h2b, float* __restrict__ a2s, float* __restrict__ a2d)
{
    __shared__ float w2s[64 * 40];      // 10.0 KB
    __shared__ float hstage[4][64];     // ELU'd layer-1 rows, one per wave

    const int tid  = threadIdx.x;
    const int lane = tid & 63;
    const int w    = tid >> 6;
    const int node = __builtin_amdgcn_readfirstlane(blockIdx.x * 4 + w);
    const int e = lane >> 3;      // edge slot 0..7
    const int c = lane & 7;       // chunk == head

    // stage W2 (coalesced float4); visibility ordered by the post-loop barrier
    #pragma unroll
    for (int i = tid; i < 640; i += 256)
        ((float4*)w2s)[i] = ((const float4*)W2)[i];

    const int start = cumS[node];
    const int end   = cumE[node];

    const float aDn = aD[(size_t)node * 8 + c];
    float acc[8] = {0.f, 0.f, 0.f, 0.f, 0.f, 0.f, 0.f, 0.f};
    float den = 0.f;

    if (e == 0) {   // self loop handled by the e==0 lane group
        const float e0 = fexp(leaky(aS[(size_t)node * 8 + c] + aDn));
        const short8 hv = *(const short8*)(h1b + (size_t)node * 64 + c * 8);
        #pragma unroll
        for (int j = 0; j < 8; ++j)
            acc[j] = e0 * bf2f((unsigned short)hv[j]);
        den = e0;
    }

    int base = start;
    // superrounds: 32 edges, 12 gathers in flight
    for (; base + 32 <= end; base += 32) {
        const int s0 = ssrc[base + e];
        const int s1 = ssrc[base + 8 + e];
        const int s2 = ssrc[base + 16 + e];
        const int s3 = ssrc[base + 24 + e];
        const float aa0 = aS[(size_t)s0 * 8 + c];
        const float aa1 = aS[(size_t)s1 * 8 + c];
        const float aa2 = aS[(size_t)s2 * 8 + c];
        const float aa3 = aS[(size_t)s3 * 8 + c];
        const short8 h0 = *(const short8*)(h1b + ((size_t)s0 << 6) + c * 8);
        const short8 h1v = *(const short8*)(h1b + ((size_t)s1 << 6) + c * 8);
        const short8 h2v = *(const short8*)(h1b + ((size_t)s2 << 6) + c * 8);
        const short8 h3v = *(const short8*)(h1b + ((size_t)s3 << 6) + c * 8);
        const float w0 = fexp(leaky(aa0 + aDn));
        const float w1 = fexp(leaky(aa1 + aDn));
        const float w2 = fexp(leaky(aa2 + aDn));
        const float w3 = fexp(leaky(aa3 + aDn));
        #pragma unroll
        for (int j = 0; j < 8; ++j) {
            acc[j] = fmaf(w0, bf2f((unsigned short)h0[j]), acc[j]);
            acc[j] = fmaf(w1, bf2f((unsigned short)h1v[j]), acc[j]);
            acc[j] = fmaf(w2, bf2f((unsigned short)h2v[j]), acc[j]);
            acc[j] = fmaf(w3, bf2f((unsigned short)h3v[j]), acc[j]);
        }
        den += w0 + w1 + w2 + w3;
    }
    // single rounds of 8
    for (; base + 8 <= end; base += 8) {
        const int s = ssrc[base + e];
        const float aa = aS[(size_t)s * 8 + c];
        const short8 hv = *(const short8*)(h1b + ((size_t)s << 6) + c * 8);
        const float wv = fexp(leaky(aa + aDn));
        #pragma unroll
        for (int j = 0; j < 8; ++j)
            acc[j] = fmaf(wv, bf2f((unsigned short)hv[j]), acc[j]);
        den += wv;
    }
    if (base < end) {          // masked tail (1..7 edges)
        const int nb  = end - base;
        const int idx = base + (e < nb ? e : nb - 1);
        const int s   = ssrc[idx];
        float wv = fexp(leaky(aS[(size_t)s * 8 + c] + aDn));
        if (e >= nb) wv = 0.f;
        const short8 hv = *(const short8*)(h1b + ((size_t)s << 6) + c * 8);
        #pragma unroll
        for (int j = 0; j < 8; ++j)
            acc[j] = fmaf(wv, bf2f((unsigned short)hv[j]), acc[j]);
        den += wv;
    }

    // reduce over e-dimension (lanes with equal c)
    #pragma unroll
    for (int m = 8; m < 64; m <<= 1) {
        den += __shfl_xor(den, m, 64);
        #pragma unroll
        for (int j = 0; j < 8; ++j)
            acc[j] += __shfl_xor(acc[j], m, 64);
    }

    if (e == 0) {   // lanes 0..7: finalize channels c*8..c*8+7 -> LDS
        const float dinv = 1.f / (den + 1e-16f);
        #pragma unroll
        for (int j = 0; j < 8; ++j) {
            const float v = acc[j] * dinv + b1[c * 8 + j];
            hstage[w][c * 8 + j] = v > 0.f ? v : (__expf(v) - 1.f);
        }
    }
    __syncthreads();   // orders w2s staging AND hstage writes for all waves

    // ---- fused gemm2: lane j computes h2[node][j] = helu_row . W2[:,j]
    const int j = lane;
    float acc2 = 0.f;
    if (j < OUT_CH) {
        #pragma unroll
        for (int k = 0; k < 64; ++k)
            acc2 = fmaf(hstage[w][k], w2s[k * 40 + j], acc2);
    }
    float vs = (j < OUT_CH) ? acc2 * attS2[j] : 0.f;
    float vd = (j < OUT_CH) ? acc2 * attD2[j] : 0.f;
    #pragma unroll
    for (int off = 32; off; off >>= 1) {
        vs += __shfl_xor(vs, off, 64);
        vd += __shfl_xor(vd, off, 64);
    }
    if (j < OUT_CH) h2b[(size_t)node * 40 + j] = f2bf(acc2);
    if (j == 0) {
        a2s[node] = vs;
        a2d[node] = vd;
    }
}

// ---------------------------------------------------------------------------
// K-AGG2: wave per node; lane = (e = lane>>3, c = lane&7), chunks 0..4 carry
// channels (h2b stride 40). Superrounds of 32 + rounds of 8 + masked tail.
// Dead lanes (c>=5) accumulate junk that is never read (cheaper than guards).
// ---------------------------------------------------------------------------
__global__ __launch_bounds__(256) void k_agg2(
    const int* __restrict__ cumS, const int* __restrict__ cumE,
    const int* __restrict__ ssrc,
    const float* __restrict__ a2s, const float* __restrict__ a2d,
    const unsigned short* __restrict__ h2b, const float* __restrict__ b2,
    float* __restrict__ out)
{
    const int lane = threadIdx.x & 63;
    const int node = __builtin_amdgcn_readfirstlane(blockIdx.x * 4 + (threadIdx.x >> 6));
    const int e = lane >> 3;
    const int c = lane & 7;

    const int start = cumS[node];
    const int end   = cumE[node];

    const float aDd = a2d[node];
    float acc[8] = {0.f, 0.f, 0.f, 0.f, 0.f, 0.f, 0.f, 0.f};
    float den = 0.f;

    if (e == 0) {
        const float e0 = fexp(leaky(a2s[node] + aDd));
        const short8 hv = *(const short8*)(h2b + (size_t)node * 40 + c * 8);
        #pragma unroll
        for (int j = 0; j < 8; ++j)
            acc[j] = e0 * bf2f((unsigned short)hv[j]);
        den = e0;
    }

    int base = start;
    for (; base + 32 <= end; base += 32) {
        const int s0 = ssrc[base + e];
        const int s1 = ssrc[base + 8 + e];
        const int s2 = ssrc[base + 16 + e];
        const int s3 = ssrc[base + 24 + e];
        const float aa0 = a2s[s0];
        const float aa1 = a2s[s1];
        const float aa2 = a2s[s2];
        const float aa3 = a2s[s3];
        const short8 h0 = *(const short8*)(h2b + (size_t)s0 * 40 + c * 8);
        const short8 h1v = *(const short8*)(h2b + (size_t)s1 * 40 + c * 8);
        const short8 h2v = *(const short8*)(h2b + (size_t)s2 * 40 + c * 8);
        const short8 h3v = *(const short8*)(h2b + (size_t)s3 * 40 + c * 8);
        const float w0 = fexp(leaky(aa0 + aDd));
        const float w1 = fexp(leaky(aa1 + aDd));
        const float w2 = fexp(leaky(aa2 + aDd));
        const float w3 = fexp(leaky(aa3 + aDd));
        #pragma unroll
        for (int j = 0; j < 8; ++j) {
            acc[j] = fmaf(w0, bf2f((unsigned short)h0[j]), acc[j]);
            acc[j] = fmaf(w1, bf2f((unsigned short)h1v[j]), acc[j]);
            acc[j] = fmaf(w2, bf2f((unsigned short)h2v[j]), acc[j]);
            acc[j] = fmaf(w3, bf2f((unsigned short)h3v[j]), acc[j]);
        }
        den += w0 + w1 + w2 + w3;
    }
    for (; base + 8 <= end; base += 8) {
        const int s = ssrc[base + e];
        const float aa = a2s[s];
        const short8 hv = *(const short8*)(h2b + (size_t)s * 40 + c * 8);
        const float wv = fexp(leaky(aa + aDd));
        #pragma unroll
        for (int j = 0; j < 8; ++j)
            acc[j] = fmaf(wv, bf2f((unsigned short)hv[j]), acc[j]);
        den += wv;
    }
    if (base < end) {
        const int nb  = end - base;
        const int idx = base + (e < nb ? e : nb - 1);
        const int s   = ssrc[idx];
        float wv = fexp(leaky(a2s[s] + aDd));
        if (e >= nb) wv = 0.f;
        const short8 hv = *(const short8*)(h2b + (size_t)s * 40 + c * 8);
        #pragma unroll
        for (int j = 0; j < 8; ++j)
            acc[j] = fmaf(wv, bf2f((unsigned short)hv[j]), acc[j]);
        den += wv;
    }

    #pragma unroll
    for (int m = 8; m < 64; m <<= 1) {
        den += __shfl_xor(den, m, 64);
        #pragma unroll
        for (int j = 0; j < 8; ++j)
            acc[j] += __shfl_xor(acc[j], m, 64);
    }

    if (e == 0 && c < 5) {   // lanes 0..4 write channels c*8..c*8+7
        const float dinv = 1.f / (den + 1e-16f);
        float o[8];
        #pragma unroll
        for (int j = 0; j < 8; ++j)
            o[j] = acc[j] * dinv + b2[c * 8 + j];
        float4* dst0 = (float4*)(out + (size_t)node * OUT_CH + c * 8);
        dst0[0] = make_float4(o[0], o[1], o[2], o[3]);
        dst0[1] = make_float4(o[4], o[5], o[6], o[7]);
    }
}

// ---------------------------------------------------------------------------
extern "C" void kernel_launch(void* const* d_in, const int* in_sizes, int n_in,
                              void* d_out, int out_size, void* d_ws, size_t ws_size,
                              hipStream_t stream)
{
    const float* x     = (const float*)d_in[0];
    const int*   ei    = (const int*)d_in[1];
    const float* W1    = (const float*)d_in[2];
    const float* attS1 = (const float*)d_in[3];
    const float* attD1 = (const float*)d_in[4];
    const float* b1    = (const float*)d_in[5];
    const float* W2    = (const float*)d_in[6];
    const float* attS2 = (const float*)d_in[7];
    const float* attD2 = (const float*)d_in[8];
    const float* b2    = (const float*)d_in[9];

    const int E = in_sizes[1] / 2;
    const int* src = ei;
    const int* dst = ei + E;

    float* out = (float*)d_out;
    float* f = (float*)d_ws;
    float* aS1  = f;  f += (size_t)N_NODES * 8;
    float* aD1  = f;  f += (size_t)N_NODES * 8;
    float* a2s  = f;  f += (size_t)N_NODES;
    float* a2d  = f;  f += (size_t)N_NODES;
    unsigned short* h1b = (unsigned short*)f;  f += (size_t)N_NODES * 32;  // bf16 [N][64]
    unsigned short* h2b = (unsigned short*)f;  f += (size_t)N_NODES * 20 + 64;  // bf16 [N][40] (+pad)
    short* bph = (short*)f;  f += 16384;        // 512*64 shorts (64 KB)
    short* bpl = (short*)f;  f += 16384;
    unsigned int* pairs = (unsigned int*)f;  f += (size_t)NB * CAP;
    int* ip = (int*)f;
    int* coarseCur = ip;  ip += 256;
    int* cumS      = ip;  ip += N_NODES;
    int* cumE      = ip;  ip += N_NODES;
    int* ssrc      = ip;  ip += (size_t)NB * CAP;

    const int partBlocks = (E + TILE - 1) / TILE;

    // ---- packW first (also inits coarse cursors; independent of edges)
    k_packW<<<(512 * 64 + 255) / 256, 256, 0, stream>>>(W1, bph, bpl, coarseCur);

    // ---- CSR build (fixed-capacity buckets; no count pass)
    k_part<<<partBlocks, 256, 0, stream>>>(src, dst, E, coarseCur, pairs);
    k_fine2<<<NB, 256, 0, stream>>>(coarseCur, pairs, ssrc, cumS, cumE);

    // ---- Layer 1 (agg fused with layer-2 GEMM + logits)
    k_gemm1_mfma<<<(N_NODES + 31) / 32, 256, 0, stream>>>(x, bph, bpl, attS1, attD1,
                                                          h1b, aS1, aD1);
    k_agg1f<<<N_NODES / 4, 256, 0, stream>>>(cumS, cumE, ssrc, aS1, aD1, h1b, b1,
                                             W2, attS2, attD2, h2b, a2s, a2d);

    // ---- Layer 2 aggregation
    k_agg2<<<N_NODES / 4, 256, 0, stream>>>(cumS, cumE, ssrc, a2s, a2d, h2b, b2, out);
}

// Round 19
// 171.257 us; speedup vs baseline: 1.1161x; 1.0387x over previous
//
#include <hip/hip_runtime.h>
#include <math.h>

#define N_NODES 50000
#define IN_CH   512
#define HID     8
#define HEADS   8
#define C1      64      // HEADS*HID
#define OUT_CH  40
#define NEG_SLOPE 0.2f
#define NB      ((N_NODES + 255) / 256)   // 196 coarse buckets (dst>>8)
#define TILE    4096                      // edges per part block
#define CAP     16384                     // per-bucket capacity (mean 8163)
#define PACKW_BLOCKS 128                  // 512*64/256
#define GEMM1_BLOCKS ((N_NODES + 31) / 32)   // 1563

__device__ __forceinline__ float leaky(float v) { return fmaxf(v, NEG_SLOPE * v); }
// logits are tiny (|a| < ~0.1): native v_exp_f32 path is exact enough (<=2ulp)
__device__ __forceinline__ float fexp(float v) { return __expf(v); }

typedef __attribute__((ext_vector_type(8))) short short8;
typedef __attribute__((ext_vector_type(4))) short short4v;
typedef __attribute__((ext_vector_type(4))) float f32x4;

__device__ __forceinline__ unsigned short f2bf(float f) {
    unsigned u = __builtin_bit_cast(unsigned, f);
    u += 0x7FFFu + ((u >> 16) & 1u);          // round-to-nearest-even
    return (unsigned short)(u >> 16);
}
__device__ __forceinline__ float bf2f(unsigned short h) {
    unsigned u = ((unsigned)h) << 16;
    return __builtin_bit_cast(float, u);
}

#define XH_STRIDE_B 272   // bytes per LDS row: 128 bf16 = 256B + 16 pad

// ---------------------------------------------------------------------------
// K-PRE (merged, independent roles): blocks 0..127 pack W1 into MFMA
// B-fragment bf16 hi/lo; blocks 128+ run the coarse edge partition.
// Cursors are zero-initialized by memset; part adds t*CAP locally.
// ---------------------------------------------------------------------------
__global__ __launch_bounds__(256) void k_pre(
    const float* __restrict__ W1, short* __restrict__ bph, short* __restrict__ bpl,
    const int* __restrict__ src, const int* __restrict__ dst, int E,
    int* __restrict__ coarseCur, unsigned int* __restrict__ pairs)
{
    __shared__ int  hist[256];
    __shared__ int  scn[256];
    __shared__ int  offs[256];
    __shared__ unsigned int  pairBuf[TILE];
    __shared__ unsigned char bktBuf[TILE];

    const int t = threadIdx.x;

    if (blockIdx.x < PACKW_BLOCKS) {
        // ---- packW role
        const int idx = blockIdx.x * 256 + t;
        const int k = idx >> 6, col = idx & 63;
        const float w = W1[idx];
        const unsigned short hi = f2bf(w);
        const unsigned short lo = f2bf(w - bf2f(hi));
        const int di = ((k >> 5) * 64 + col) * 32 + (k & 31);
        bph[di] = (short)hi;
        bpl[di] = (short)lo;
        return;
    }

    // ---- coarse partition role
    const int tileBase = (blockIdx.x - PACKW_BLOCKS) * TILE;
    const int n = min(TILE, E - tileBase);

    hist[t] = 0;
    __syncthreads();

    for (int e = t; e < n; e += 256)
        atomicAdd(&hist[dst[tileBase + e] >> 8], 1);
    __syncthreads();

    scn[t] = hist[t];
    __syncthreads();
    #pragma unroll
    for (int off = 1; off < 256; off <<= 1) {
        int xv = (t >= off) ? scn[t - off] : 0;
        __syncthreads();
        scn[t] += xv;
        __syncthreads();
    }

    {
        const int h  = hist[t];
        const int ls = scn[t] - h;
        int off = 0;
        if (h > 0) {
            const int gbase = t * CAP + atomicAdd(&coarseCur[t], h);
            off = gbase - ls;
        }
        offs[t] = off;
        hist[t] = ls;
    }
    __syncthreads();

    for (int e = t; e < n; e += 256) {
        const int s = src[tileBase + e];
        const int d = dst[tileBase + e];
        const int bkt = d >> 8;
        const int pos = atomicAdd(&hist[bkt], 1);
        pairBuf[pos] = (unsigned)s | ((unsigned)(d & 255) << 17);
        bktBuf[pos]  = (unsigned char)bkt;
    }
    __syncthreads();

    for (int i = t; i < n; i += 256)
        pairs[i + offs[bktBuf[i]]] = pairBuf[i];
}

// ---------------------------------------------------------------------------
// K-MID (merged, independent roles): blocks 0..GEMM1_BLOCKS-1 run the MFMA
// gemm1 (h1 = (x@W1)/rowsum, bf16x3); blocks GEMM1_BLOCKS+ run the fine
// scatter (per-bucket histogram -> scan -> cumS/cumE -> ssrc).
// fine2 aliases the first 3KB of the gemm1 LDS buffer.
// ---------------------------------------------------------------------------
__global__ __launch_bounds__(256) void k_mid(
    const float* __restrict__ x,
    const short* __restrict__ bph, const short* __restrict__ bpl,
    const float* __restrict__ attS, const float* __restrict__ attD,
    unsigned short* __restrict__ h1b, float* __restrict__ aS, float* __restrict__ aD,
    const int* __restrict__ coarseCur, const unsigned int* __restrict__ pairs,
    int* __restrict__ ssrc, int* __restrict__ cumS, int* __restrict__ cumE)
{
    __shared__ unsigned char smem[17536];

    const int tid = threadIdx.x;

    if (blockIdx.x >= GEMM1_BLOCKS) {
        // ---- fine scatter role
        int* hist = (int*)smem;
        int* scn  = hist + 256;
        int* cur  = scn + 256;
        const int b = blockIdx.x - GEMM1_BLOCKS;
        const int t = tid;
        const int dbase = b << 8;
        const int nd = min(256, N_NODES - dbase);
        const int lo = b * CAP;
        const int hi = lo + coarseCur[b];     // count now relative

        hist[t] = 0;
        __syncthreads();
        for (int j = lo + t; j < hi; j += 256)
            atomicAdd(&hist[(pairs[j] >> 17) & 255], 1);
        __syncthreads();

        const int hv = hist[t];
        scn[t] = hv;
        __syncthreads();
        #pragma unroll
        for (int off = 1; off < 256; off <<= 1) {
            int xv = (t >= off) ? scn[t - off] : 0;
            __syncthreads();
            scn[t] += xv;
            __syncthreads();
        }
        if (t < nd) {
            cumS[dbase + t] = lo + scn[t] - hv;
            cumE[dbase + t] = lo + scn[t];
        }
        cur[t] = lo + scn[t] - hv;
        __syncthreads();

        for (int j = lo + t; j < hi; j += 256) {
            const unsigned int p = pairs[j];
            const int pos = atomicAdd(&cur[(p >> 17) & 255], 1);
            ssrc[pos] = (int)(p & 0x1FFFFu);
        }
        return;
    }

    // ---- gemm1 role
    short* xh = (short*)smem;                      // [32] rows x 136 shorts
    short* xl = (short*)(smem + 8704);
    float* rowsum = (float*)(smem + 17408);        // [32]
    float* houtf  = (float*)smem;                  // [32][68] (aliases xh/xl)

    const int lane = tid & 63;
    const int w    = tid >> 6;
    const int row_off = (w & 1) * 16;
    const int col_off = (w >> 1) * 32;
    const int rowBase = blockIdx.x * 32;

    const int l15 = lane & 15;
    const int kg  = lane >> 4;
    const int a_base = (l15 + row_off) * XH_STRIDE_B + kg * 16;

    const int srow = tid >> 5;          // staging row-group 0..7
    const int sk4  = tid & 31;          // staging k4 slot

    f32x4 acc0 = {0.f, 0.f, 0.f, 0.f};
    f32x4 acc1 = {0.f, 0.f, 0.f, 0.f};
    float psum[4] = {0.f, 0.f, 0.f, 0.f};
    float4 va[4], vb[4];

    auto LOAD = [&](int c, float4 (&v)[4]) {
        #pragma unroll
        for (int i = 0; i < 4; ++i) {
            const int grow = rowBase + i * 8 + srow;
            v[i] = (grow < N_NODES)
                 ? *(const float4*)(x + (size_t)grow * IN_CH + c * 128 + sk4 * 4)
                 : make_float4(0.f, 0.f, 0.f, 0.f);
        }
    };
    auto STAGE = [&](float4 (&v)[4]) {
        #pragma unroll
        for (int i = 0; i < 4; ++i) {
            const int row = i * 8 + srow;
            const unsigned short h0 = f2bf(v[i].x), h1u = f2bf(v[i].y),
                                 h2 = f2bf(v[i].z), h3  = f2bf(v[i].w);
            short4v hvv = { (short)h0, (short)h1u, (short)h2, (short)h3 };
            short4v lvv = { (short)f2bf(v[i].x - bf2f(h0)), (short)f2bf(v[i].y - bf2f(h1u)),
                            (short)f2bf(v[i].z - bf2f(h2)), (short)f2bf(v[i].w - bf2f(h3)) };
            *(short4v*)((char*)xh + row * XH_STRIDE_B + sk4 * 8) = hvv;
            *(short4v*)((char*)xl + row * XH_STRIDE_B + sk4 * 8) = lvv;
            psum[i] += v[i].x + v[i].y + v[i].z + v[i].w;
        }
    };
    auto MFMA = [&](int c) {
        #pragma unroll
        for (int kk2 = 0; kk2 < 4; ++kk2) {
            const int kk = c * 4 + kk2;
            const short8 ah = *(const short8*)((const char*)xh + a_base + kk2 * 64);
            const short8 al = *(const short8*)((const char*)xl + a_base + kk2 * 64);
            const int b0 = (kk * 64 + col_off + l15) * 32 + kg * 8;
            const int b1 = b0 + 16 * 32;
            const short8 bh0 = *(const short8*)(bph + b0);
            const short8 bl0 = *(const short8*)(bpl + b0);
            const short8 bh1 = *(const short8*)(bph + b1);
            const short8 bl1 = *(const short8*)(bpl + b1);
            acc0 = __builtin_amdgcn_mfma_f32_16x16x32_bf16(ah, bh0, acc0, 0, 0, 0);
            acc1 = __builtin_amdgcn_mfma_f32_16x16x32_bf16(ah, bh1, acc1, 0, 0, 0);
            acc0 = __builtin_amdgcn_mfma_f32_16x16x32_bf16(ah, bl0, acc0, 0, 0, 0);
            acc1 = __builtin_amdgcn_mfma_f32_16x16x32_bf16(ah, bl1, acc1, 0, 0, 0);
            acc0 = __builtin_amdgcn_mfma_f32_16x16x32_bf16(al, bh0, acc0, 0, 0, 0);
            acc1 = __builtin_amdgcn_mfma_f32_16x16x32_bf16(al, bh1, acc1, 0, 0, 0);
        }
    };

    LOAD(0, va);
    STAGE(va);
    __syncthreads();
    LOAD(1, vb);
    MFMA(0);
    __syncthreads();
    STAGE(vb);
    __syncthreads();
    LOAD(2, va);
    MFMA(1);
    __syncthreads();
    STAGE(va);
    __syncthreads();
    LOAD(3, vb);
    MFMA(2);
    __syncthreads();
    STAGE(vb);
    #pragma unroll
    for (int i = 0; i < 4; ++i) {
        float s = psum[i];
        #pragma unroll
        for (int off = 16; off; off >>= 1) s += __shfl_xor(s, off, 32);
        if (sk4 == 0) rowsum[i * 8 + srow] = s;
    }
    __syncthreads();
    MFMA(3);
    __syncthreads();

    #pragma unroll
    for (int r = 0; r < 4; ++r) {
        const int row = row_off + kg * 4 + r;   // C/D: row=(lane>>4)*4+reg
        const float rs = fmaxf(rowsum[row], 1e-8f);
        houtf[row * 68 + col_off + l15]      = acc0[r] / rs;
        houtf[row * 68 + col_off + 16 + l15] = acc1[r] / rs;
    }
    __syncthreads();

    // coalesced h1 write (bf16)
    #pragma unroll
    for (int i = tid; i < 32 * 16; i += 256) {
        const int row = i >> 4, seg = i & 15;
        if (rowBase + row < N_NODES) {
            const float* hs = houtf + row * 68 + seg * 4;
            short4v o = { (short)f2bf(hs[0]), (short)f2bf(hs[1]),
                          (short)f2bf(hs[2]), (short)f2bf(hs[3]) };
            *(short4v*)(h1b + (size_t)(rowBase + row) * 64 + seg * 4) = o;
        }
    }

    // logits: thread = (row, head), from fp32 LDS copy
    {
        const int row = tid >> 3, hd = tid & 7;
        if (rowBase + row < N_NODES) {
            float vs = 0.f, vd = 0.f;
            #pragma unroll
            for (int e2 = 0; e2 < 8; ++e2) {
                const float hv = houtf[row * 68 + hd * 8 + e2];
                vs = fmaf(hv, attS[hd * 8 + e2], vs);
                vd = fmaf(hv, attD[hd * 8 + e2], vd);
            }
            aS[(size_t)(rowBase + row) * 8 + hd] = vs;
            aD[(size_t)(rowBase + row) * 8 + hd] = vd;
        }
    }
}

// ---------------------------------------------------------------------------
// K-AGG1F: wave per node; lane = (edge e = lane>>3, chunk c = lane&7).
// Superrounds of 32 edges (12 gathers in flight) + rounds of 8 + masked tail.
// FUSED epilogue: ELU -> LDS -> gemm2 (64x40 matvec) -> h2b + logits.
// ---------------------------------------------------------------------------
__global__ __launch_bounds__(256) void k_agg1f(
    const int* __restrict__ cumS, const int* __restrict__ cumE,
    const int* __restrict__ ssrc,
    const float* __restrict__ aS, const float* __restrict__ aD,
    const unsigned short* __restrict__ h1b, const float* __restrict__ b1,
    const float* __restrict__ W2,
    const float* __restrict__ attS2, const float* __restrict__ attD2,
    unsigned short* __restrict__ h2b, float* __restrict__ a2s, float* __restrict__ a2d)
{
    __shared__ float w2s[64 * 40];      // 10.0 KB
    __shared__ float hstage[4][64];     // ELU'd layer-1 rows, one per wave

    const int tid  = threadIdx.x;
    const int lane = tid & 63;
    const int w    = tid >> 6;
    const int node = __builtin_amdgcn_readfirstlane(blockIdx.x * 4 + w);
    const int e = lane >> 3;      // edge slot 0..7
    const int c = lane & 7;       // chunk == head

    // stage W2 (coalesced float4); visibility ordered by the post-loop barrier
    #pragma unroll
    for (int i = tid; i < 640; i += 256)
        ((float4*)w2s)[i] = ((const float4*)W2)[i];

    const int start = cumS[node];
    const int end   = cumE[node];

    const float aDn = aD[(size_t)node * 8 + c];
    float acc[8] = {0.f, 0.f, 0.f, 0.f, 0.f, 0.f, 0.f, 0.f};
    float den = 0.f;

    if (e == 0) {   // self loop handled by the e==0 lane group
        const float e0 = fexp(leaky(aS[(size_t)node * 8 + c] + aDn));
        const short8 hv = *(const short8*)(h1b + (size_t)node * 64 + c * 8);
        #pragma unroll
        for (int j = 0; j < 8; ++j)
            acc[j] = e0 * bf2f((unsigned short)hv[j]);
        den = e0;
    }

    int base = start;
    // superrounds: 32 edges, 12 gathers in flight
    for (; base + 32 <= end; base += 32) {
        const int s0 = ssrc[base + e];
        const int s1 = ssrc[base + 8 + e];
        const int s2 = ssrc[base + 16 + e];
        const int s3 = ssrc[base + 24 + e];
        const float aa0 = aS[(size_t)s0 * 8 + c];
        const float aa1 = aS[(size_t)s1 * 8 + c];
        const float aa2 = aS[(size_t)s2 * 8 + c];
        const float aa3 = aS[(size_t)s3 * 8 + c];
        const short8 h0 = *(const short8*)(h1b + ((size_t)s0 << 6) + c * 8);
        const short8 h1v = *(const short8*)(h1b + ((size_t)s1 << 6) + c * 8);
        const short8 h2v = *(const short8*)(h1b + ((size_t)s2 << 6) + c * 8);
        const short8 h3v = *(const short8*)(h1b + ((size_t)s3 << 6) + c * 8);
        const float w0 = fexp(leaky(aa0 + aDn));
        const float w1 = fexp(leaky(aa1 + aDn));
        const float w2 = fexp(leaky(aa2 + aDn));
        const float w3 = fexp(leaky(aa3 + aDn));
        #pragma unroll
        for (int j = 0; j < 8; ++j) {
            acc[j] = fmaf(w0, bf2f((unsigned short)h0[j]), acc[j]);
            acc[j] = fmaf(w1, bf2f((unsigned short)h1v[j]), acc[j]);
            acc[j] = fmaf(w2, bf2f((unsigned short)h2v[j]), acc[j]);
            acc[j] = fmaf(w3, bf2f((unsigned short)h3v[j]), acc[j]);
        }
        den += w0 + w1 + w2 + w3;
    }
    // single rounds of 8
    for (; base + 8 <= end; base += 8) {
        const int s = ssrc[base + e];
        const float aa = aS[(size_t)s * 8 + c];
        const short8 hv = *(const short8*)(h1b + ((size_t)s << 6) + c * 8);
        const float wv = fexp(leaky(aa + aDn));
        #pragma unroll
        for (int j = 0; j < 8; ++j)
            acc[j] = fmaf(wv, bf2f((unsigned short)hv[j]), acc[j]);
        den += wv;
    }
    if (base < end) {          // masked tail (1..7 edges)
        const int nb  = end - base;
        const int idx = base + (e < nb ? e : nb - 1);
        const int s   = ssrc[idx];
        float wv = fexp(leaky(aS[(size_t)s * 8 + c] + aDn));
        if (e >= nb) wv = 0.f;
        const short8 hv = *(const short8*)(h1b + ((size_t)s << 6) + c * 8);
        #pragma unroll
        for (int j = 0; j < 8; ++j)
            acc[j] = fmaf(wv, bf2f((unsigned short)hv[j]), acc[j]);
        den += wv;
    }

    // reduce over e-dimension (lanes with equal c)
    #pragma unroll
    for (int m = 8; m < 64; m <<= 1) {
        den += __shfl_xor(den, m, 64);
        #pragma unroll
        for (int j = 0; j < 8; ++j)
            acc[j] += __shfl_xor(acc[j], m, 64);
    }

    if (e == 0) {   // lanes 0..7: finalize channels c*8..c*8+7 -> LDS
        const float dinv = 1.f / (den + 1e-16f);
        #pragma unroll
        for (int j = 0; j < 8; ++j) {
            const float v = acc[j] * dinv + b1[c * 8 + j];
            hstage[w][c * 8 + j] = v > 0.f ? v : (__expf(v) - 1.f);
        }
    }
    __syncthreads();   // orders w2s staging AND hstage writes for all waves

    // ---- fused gemm2: lane j computes h2[node][j] = helu_row . W2[:,j]
    const int j = lane;
    float acc2 = 0.f;
    if (j < OUT_CH) {
        #pragma unroll
        for (int k = 0; k < 64; ++k)
            acc2 = fmaf(hstage[w][k], w2s[k * 40 + j], acc2);
    }
    float vs = (j < OUT_CH) ? acc2 * attS2[j] : 0.f;
    float vd = (j < OUT_CH) ? acc2 * attD2[j] : 0.f;
    #pragma unroll
    for (int off = 32; off; off >>= 1) {
        vs += __shfl_xor(vs, off, 64);
        vd += __shfl_xor(vd, off, 64);
    }
    if (j < OUT_CH) h2b[(size_t)node * 40 + j] = f2bf(acc2);
    if (j == 0) {
        a2s[node] = vs;
        a2d[node] = vd;
    }
}

// ---------------------------------------------------------------------------
// K-AGG2: wave per node; lane = (e = lane>>3, c = lane&7), chunks 0..4 carry
// channels (h2b stride 40). Superrounds of 32 + rounds of 8 + masked tail.
// Dead lanes (c>=5) accumulate junk that is never read (cheaper than guards).
// ---------------------------------------------------------------------------
__global__ __launch_bounds__(256) void k_agg2(
    const int* __restrict__ cumS, const int* __restrict__ cumE,
    const int* __restrict__ ssrc,
    const float* __restrict__ a2s, const float* __restrict__ a2d,
    const unsigned short* __restrict__ h2b, const float* __restrict__ b2,
    float* __restrict__ out)
{
    const int lane = threadIdx.x & 63;
    const int node = __builtin_amdgcn_readfirstlane(blockIdx.x * 4 + (threadIdx.x >> 6));
    const int e = lane >> 3;
    const int c = lane & 7;

    const int start = cumS[node];
    const int end   = cumE[node];

    const float aDd = a2d[node];
    float acc[8] = {0.f, 0.f, 0.f, 0.f, 0.f, 0.f, 0.f, 0.f};
    float den = 0.f;

    if (e == 0) {
        const float e0 = fexp(leaky(a2s[node] + aDd));
        const short8 hv = *(const short8*)(h2b + (size_t)node * 40 + c * 8);
        #pragma unroll
        for (int j = 0; j < 8; ++j)
            acc[j] = e0 * bf2f((unsigned short)hv[j]);
        den = e0;
    }

    int base = start;
    for (; base + 32 <= end; base += 32) {
        const int s0 = ssrc[base + e];
        const int s1 = ssrc[base + 8 + e];
        const int s2 = ssrc[base + 16 + e];
        const int s3 = ssrc[base + 24 + e];
        const float aa0 = a2s[s0];
        const float aa1 = a2s[s1];
        const float aa2 = a2s[s2];
        const float aa3 = a2s[s3];
        const short8 h0 = *(const short8*)(h2b + (size_t)s0 * 40 + c * 8);
        const short8 h1v = *(const short8*)(h2b + (size_t)s1 * 40 + c * 8);
        const short8 h2v = *(const short8*)(h2b + (size_t)s2 * 40 + c * 8);
        const short8 h3v = *(const short8*)(h2b + (size_t)s3 * 40 + c * 8);
        const float w0 = fexp(leaky(aa0 + aDd));
        const float w1 = fexp(leaky(aa1 + aDd));
        const float w2 = fexp(leaky(aa2 + aDd));
        const float w3 = fexp(leaky(aa3 + aDd));
        #pragma unroll
        for (int j = 0; j < 8; ++j) {
            acc[j] = fmaf(w0, bf2f((unsigned short)h0[j]), acc[j]);
            acc[j] = fmaf(w1, bf2f((unsigned short)h1v[j]), acc[j]);
            acc[j] = fmaf(w2, bf2f((unsigned short)h2v[j]), acc[j]);
            acc[j] = fmaf(w3, bf2f((unsigned short)h3v[j]), acc[j]);
        }
        den += w0 + w1 + w2 + w3;
    }
    for (; base + 8 <= end; base += 8) {
        const int s = ssrc[base + e];
        const float aa = a2s[s];
        const short8 hv = *(const short8*)(h2b + (size_t)s * 40 + c * 8);
        const float wv = fexp(leaky(aa + aDd));
        #pragma unroll
        for (int j = 0; j < 8; ++j)
            acc[j] = fmaf(wv, bf2f((unsigned short)hv[j]), acc[j]);
        den += wv;
    }
    if (base < end) {
        const int nb  = end - base;
        const int idx = base + (e < nb ? e : nb - 1);
        const int s   = ssrc[idx];
        float wv = fexp(leaky(a2s[s] + aDd));
        if (e >= nb) wv = 0.f;
        const short8 hv = *(const short8*)(h2b + (size_t)s * 40 + c * 8);
        #pragma unroll
        for (int j = 0; j < 8; ++j)
            acc[j] = fmaf(wv, bf2f((unsigned short)hv[j]), acc[j]);
        den += wv;
    }

    #pragma unroll
    for (int m = 8; m < 64; m <<= 1) {
        den += __shfl_xor(den, m, 64);
        #pragma unroll
        for (int j = 0; j < 8; ++j)
            acc[j] += __shfl_xor(acc[j], m, 64);
    }

    if (e == 0 && c < 5) {   // lanes 0..4 write channels c*8..c*8+7
        const float dinv = 1.f / (den + 1e-16f);
        float o[8];
        #pragma unroll
        for (int j = 0; j < 8; ++j)
            o[j] = acc[j] * dinv + b2[c * 8 + j];
        float4* dst0 = (float4*)(out + (size_t)node * OUT_CH + c * 8);
        dst0[0] = make_float4(o[0], o[1], o[2], o[3]);
        dst0[1] = make_float4(o[4], o[5], o[6], o[7]);
    }
}

// ---------------------------------------------------------------------------
extern "C" void kernel_launch(void* const* d_in, const int* in_sizes, int n_in,
                              void* d_out, int out_size, void* d_ws, size_t ws_size,
                              hipStream_t stream)
{
    const float* x     = (const float*)d_in[0];
    const int*   ei    = (const int*)d_in[1];
    const float* W1    = (const float*)d_in[2];
    const float* attS1 = (const float*)d_in[3];
    const float* attD1 = (const float*)d_in[4];
    const float* b1    = (const float*)d_in[5];
    const float* W2    = (const float*)d_in[6];
    const float* attS2 = (const float*)d_in[7];
    const float* attD2 = (const float*)d_in[8];
    const float* b2    = (const float*)d_in[9];

    const int E = in_sizes[1] / 2;
    const int* src = ei;
    const int* dst = ei + E;

    float* out = (float*)d_out;
    float* f = (float*)d_ws;
    float* aS1  = f;  f += (size_t)N_NODES * 8;
    float* aD1  = f;  f += (size_t)N_NODES * 8;
    float* a2s  = f;  f += (size_t)N_NODES;
    float* a2d  = f;  f += (size_t)N_NODES;
    unsigned short* h1b = (unsigned short*)f;  f += (size_t)N_NODES * 32;  // bf16 [N][64]
    unsigned short* h2b = (unsigned short*)f;  f += (size_t)N_NODES * 20 + 64;  // bf16 [N][40] (+pad)
    short* bph = (short*)f;  f += 16384;        // 512*64 shorts (64 KB)
    short* bpl = (short*)f;  f += 16384;
    unsigned int* pairs = (unsigned int*)f;  f += (size_t)NB * CAP;
    int* ip = (int*)f;
    int* coarseCur = ip;  ip += 256;
    int* cumS      = ip;  ip += N_NODES;
    int* cumE      = ip;  ip += N_NODES;
    int* ssrc      = ip;  ip += (size_t)NB * CAP;

    const int partBlocks = (E + TILE - 1) / TILE;

    // cursors zeroed (part adds the b*CAP base locally)
    hipMemsetAsync(coarseCur, 0, 256 * sizeof(int), stream);

    // ---- phase 1: packW || coarse partition (independent roles, one launch)
    k_pre<<<PACKW_BLOCKS + partBlocks, 256, 0, stream>>>(W1, bph, bpl,
                                                         src, dst, E, coarseCur, pairs);

    // ---- phase 2: gemm1 (MFMA) || fine scatter (independent roles)
    k_mid<<<GEMM1_BLOCKS + NB, 256, 0, stream>>>(x, bph, bpl, attS1, attD1,
                                                 h1b, aS1, aD1,
                                                 coarseCur, pairs, ssrc, cumS, cumE);

    // ---- layer-1 aggregation fused with layer-2 GEMM + logits
    k_agg1f<<<N_NODES / 4, 256, 0, stream>>>(cumS, cumE, ssrc, aS1, aD1, h1b, b1,
                                             W2, attS2, attD2, h2b, a2s, a2d);

    // ---- layer-2 aggregation
    k_agg2<<<N_NODES / 4, 256, 0, stream>>>(cumS, cumE, ssrc, a2s, a2d, h2b, b2, out);
}